// Round 7
// baseline (717.973 us; speedup 1.0000x reference)
//
#include <hip/hip_runtime.h>

#define DIM 64
#define SCAN_ELEMS 1024   // elements per scan block (256 threads x 4)
#define CHUNK 16384       // edges per partition block
#define BSHIFT 11         // 2048 nodes per coarse bucket
#define MAXB 128          // max coarse buckets (N<=262144)
#define NXCD 8

// ---- bf16 helpers (RNE) ----
__device__ __forceinline__ unsigned f2bf(float f) {
    unsigned u = __float_as_uint(f);
    return (u + 0x7FFFu + ((u >> 16) & 1u)) >> 16;
}
__device__ __forceinline__ float bflo(unsigned u) {   // low u16 -> f32
    return __uint_as_float(u << 16);
}
__device__ __forceinline__ float bfhi(unsigned u) {   // high u16 -> f32
    return __uint_as_float(u & 0xFFFF0000u);
}

// bijective XCD swizzle (m204 variant): consecutive data chunks stay on one XCD
__device__ __forceinline__ int xcd_swizzle(int bid, int nwg) {
    int q = nwg >> 3, r = nwg & 7;
    int x = bid & 7, i = bid >> 3;
    int base = (x < r) ? x * (q + 1) : r * (q + 1) + (x - r) * q;
    return base + i;
}

// ---------------- zero u32 region ----------------
__global__ void zero_u32(unsigned* __restrict__ p, int n) {
    int i = blockIdx.x * blockDim.x + threadIdx.x;
    int stride = gridDim.x * blockDim.x;
    for (; i < n; i += stride) p[i] = 0u;
}

// ---------------- degree histogram over h_list (int atomics) ----------------
__global__ void count_deg(const int* __restrict__ h, unsigned* __restrict__ cnt, int E) {
    int i = blockIdx.x * blockDim.x + threadIdx.x;
    if (i < E) atomicAdd(&cnt[h[i]], 1u);
}

// ---------------- convert concat(ue,ie) f32 -> bf16 table ----------------
__global__ void cvt_x0(const float* __restrict__ ue, const float* __restrict__ ie,
                       long nu_elems, unsigned short* __restrict__ x0h, long M) {
    long i4 = ((long)blockIdx.x * blockDim.x + threadIdx.x) * 4;
    long stride = (long)gridDim.x * blockDim.x * 4;
    for (; i4 < M; i4 += stride) {
        const float* src = (i4 < nu_elems) ? ue + i4 : ie + (i4 - nu_elems);
        float4 v = *(const float4*)src;
        ushort4 o;
        o.x = (unsigned short)f2bf(v.x); o.y = (unsigned short)f2bf(v.y);
        o.z = (unsigned short)f2bf(v.z); o.w = (unsigned short)f2bf(v.w);
        *(ushort4*)(x0h + i4) = o;
    }
}

// ---------------- scan step 1: per-block sums over counts ----------------
__global__ void block_reduce_counts(const unsigned* __restrict__ cnt,
                                    unsigned* __restrict__ bsum, int N) {
    __shared__ unsigned s[256];
    int tid = threadIdx.x;
    long base = (long)blockIdx.x * SCAN_ELEMS + tid * 4;
    unsigned sum = 0;
    #pragma unroll
    for (int j = 0; j < 4; ++j) { long i = base + j; if (i < N) sum += cnt[i]; }
    s[tid] = sum; __syncthreads();
    for (int off = 128; off > 0; off >>= 1) {
        if (tid < off) s[tid] += s[tid + off];
        __syncthreads();
    }
    if (tid == 0) bsum[blockIdx.x] = s[0];
}

// ---------------- scan step 2: exclusive scan of block sums (1 block) ----------------
__global__ void scan_block_sums(unsigned* __restrict__ bsum, int nb,
                                unsigned* __restrict__ row_ptr, int N, int E) {
    __shared__ unsigned s[256];
    int tid = threadIdx.x;
    unsigned running = 0;
    for (int base = 0; base < nb; base += 256) {
        int i = base + tid;
        unsigned v = (i < nb) ? bsum[i] : 0u;
        s[tid] = v; __syncthreads();
        for (int off = 1; off < 256; off <<= 1) {
            unsigned t = (tid >= off) ? s[tid - off] : 0u;
            __syncthreads();
            s[tid] += t; __syncthreads();
        }
        unsigned incl = s[tid];
        if (i < nb) bsum[i] = running + (incl - v);   // exclusive
        unsigned total = s[255];
        __syncthreads();
        running += total;
    }
    if (tid == 0) row_ptr[N] = (unsigned)E;
}

// ---------------- scan step 3: intra-block scan -> row_ptr (+ fused rdeg) ----------------
__global__ void scan_within_block(const unsigned* __restrict__ cnt,
                                  const unsigned* __restrict__ bsum,
                                  unsigned* __restrict__ row_ptr,
                                  float* __restrict__ rdeg, int N) {
    __shared__ unsigned s[256];
    int tid = threadIdx.x;
    long base = (long)blockIdx.x * SCAN_ELEMS + tid * 4;
    unsigned c[4]; unsigned lsum = 0;
    #pragma unroll
    for (int j = 0; j < 4; ++j) {
        c[j] = (base + j < N) ? cnt[base + j] : 0u;
        lsum += c[j];
    }
    s[tid] = lsum; __syncthreads();
    for (int off = 1; off < 256; off <<= 1) {
        unsigned t = (tid >= off) ? s[tid - off] : 0u;
        __syncthreads();
        s[tid] += t; __syncthreads();
    }
    unsigned off = bsum[blockIdx.x] + (s[tid] - lsum);
    #pragma unroll
    for (int j = 0; j < 4; ++j) {
        if (base + j < N) {
            row_ptr[base + j] = off;
            rdeg[base + j] = rsqrtf(fmaxf((float)c[j], 1.0f));
            off += c[j];
        }
    }
}

// ---------------- init coarse-bucket cursors: bcur[b] = rp[min(b<<BSHIFT, N)] ----------------
__global__ void init_bcur(const unsigned* __restrict__ rp, unsigned* __restrict__ bcur,
                          int nb, int N) {
    int i = blockIdx.x * blockDim.x + threadIdx.x;
    if (i < nb) {
        long node = (long)i << BSHIFT;
        if (node > N) node = N;
        bcur[i] = rp[node];
    }
}

// ---------------- coarse partition: (h,t) pairs -> bucket-contiguous tmp ----------------
__global__ void partition_edges(const int* __restrict__ h, const int* __restrict__ t,
                                unsigned* __restrict__ bcur, int2* __restrict__ tmp,
                                int E, int nb) {
    __shared__ unsigned cnt[MAXB];
    int tid = threadIdx.x;
    long start = (long)blockIdx.x * CHUNK;
    long end = start + CHUNK; if (end > E) end = E;
    for (int i = tid; i < nb; i += blockDim.x) cnt[i] = 0u;
    __syncthreads();
    for (long i = start + tid; i < end; i += blockDim.x)
        atomicAdd(&cnt[((unsigned)h[i]) >> BSHIFT], 1u);
    __syncthreads();
    for (int i = tid; i < nb; i += blockDim.x) {
        unsigned c = cnt[i];
        cnt[i] = c ? atomicAdd(&bcur[i], c) : 0u;   // reserve chunk; cnt becomes cursor
    }
    __syncthreads();
    for (long i = start + tid; i < end; i += blockDim.x) {
        int hn = h[i], tn = t[i];
        unsigned pos = atomicAdd(&cnt[((unsigned)hn) >> BSHIFT], 1u);
        tmp[pos] = make_int2(hn, tn);
    }
}

// ---------------- fine scatter: bucket-partitioned pairs -> exact CSR position ----------------
// XCD-swizzled so each XCD owns a contiguous ~E/8 slice: its ~2MB col window
// stays in its own L2 -> lines merge before eviction (kills 12x write-amp).
__global__ void scatter_csr(const int2* __restrict__ tmp, unsigned* __restrict__ cursor,
                            int* __restrict__ col, int E) {
    int db = xcd_swizzle(blockIdx.x, gridDim.x);
    int i = db * blockDim.x + threadIdx.x;
    if (i >= E) return;
    int2 e = tmp[i];
    unsigned pos = atomicAdd(&cursor[e.x], 1u);
    col[pos] = e.y;
}

// ---------------- pull SpMM layer 1: x1 = G @ x0 ----------------
// Four edges per wave: 16-lane group g handles edge e+g; each lane loads one
// u64 (4 bf16 dims). Quarters VMEM/addr instrs per edge vs full-wave rows.
__global__ void spmm_pull_l1(const unsigned* __restrict__ rp,
                             const int* __restrict__ col,
                             const float* __restrict__ rdeg,
                             const uint2* __restrict__ x0q,
                             uint2* __restrict__ x1q, int N) {
    int node = blockIdx.x * (blockDim.x >> 6) + (threadIdx.x >> 6);
    int lane = threadIdx.x & 63;
    int g  = lane >> 4;     // edge slot 0..3
    int hl = lane & 15;     // dim quad 0..15
    if (node >= N) return;
    int e0 = __builtin_amdgcn_readfirstlane((int)rp[node]);
    int e1 = __builtin_amdgcn_readfirstlane((int)rp[node + 1]);
    float a0 = 0.f, a1 = 0.f, a2 = 0.f, a3 = 0.f;
    int e = e0;
    for (; e + 8 <= e1; e += 8) {     // 8 edges in flight
        int cA = col[e + g],     cB = col[e + 4 + g];
        float wA = rdeg[cA],     wB = rdeg[cB];
        uint2 uA = x0q[((size_t)cA << 4) + hl];
        uint2 uB = x0q[((size_t)cB << 4) + hl];
        a0 += wA * bflo(uA.x); a1 += wA * bfhi(uA.x);
        a2 += wA * bflo(uA.y); a3 += wA * bfhi(uA.y);
        a0 += wB * bflo(uB.x); a1 += wB * bfhi(uB.x);
        a2 += wB * bflo(uB.y); a3 += wB * bfhi(uB.y);
    }
    for (; e + 4 <= e1; e += 4) {
        int c = col[e + g];
        float wv = rdeg[c];
        uint2 u = x0q[((size_t)c << 4) + hl];
        a0 += wv * bflo(u.x); a1 += wv * bfhi(u.x);
        a2 += wv * bflo(u.y); a3 += wv * bfhi(u.y);
    }
    if (e < e1) {                     // masked tail: 1..3 edges
        int idx = e + g;
        if (idx < e1) {
            int c = col[idx];
            float wv = rdeg[c];
            uint2 u = x0q[((size_t)c << 4) + hl];
            a0 += wv * bflo(u.x); a1 += wv * bfhi(u.x);
            a2 += wv * bflo(u.y); a3 += wv * bfhi(u.y);
        }
    }
    // reduce across the 4 edge slots (lanes differing in bits 4,5)
    a0 += __shfl_xor(a0, 16); a1 += __shfl_xor(a1, 16);
    a2 += __shfl_xor(a2, 16); a3 += __shfl_xor(a3, 16);
    a0 += __shfl_xor(a0, 32); a1 += __shfl_xor(a1, 32);
    a2 += __shfl_xor(a2, 32); a3 += __shfl_xor(a3, 32);
    if (g == 0) {
        float rd = rdeg[node];
        uint2 o;
        o.x = (f2bf(rd * a1) << 16) | f2bf(rd * a0);
        o.y = (f2bf(rd * a3) << 16) | f2bf(rd * a2);
        x1q[((size_t)node << 4) + hl] = o;
    }
}

// ---------------- pull SpMM layer 2 fused with finalize ----------------
__global__ void spmm_l2_finalize(const unsigned* __restrict__ rp,
                                 const int* __restrict__ col,
                                 const float* __restrict__ rdeg,
                                 const uint2* __restrict__ x0q,
                                 const uint2* __restrict__ x1q,
                                 float* __restrict__ out, int N) {
    int node = blockIdx.x * (blockDim.x >> 6) + (threadIdx.x >> 6);
    int lane = threadIdx.x & 63;
    int g  = lane >> 4;
    int hl = lane & 15;
    if (node >= N) return;
    int e0 = __builtin_amdgcn_readfirstlane((int)rp[node]);
    int e1 = __builtin_amdgcn_readfirstlane((int)rp[node + 1]);
    float a0 = 0.f, a1 = 0.f, a2 = 0.f, a3 = 0.f;
    int e = e0;
    for (; e + 8 <= e1; e += 8) {
        int cA = col[e + g],     cB = col[e + 4 + g];
        float wA = rdeg[cA],     wB = rdeg[cB];
        uint2 uA = x1q[((size_t)cA << 4) + hl];
        uint2 uB = x1q[((size_t)cB << 4) + hl];
        a0 += wA * bflo(uA.x); a1 += wA * bfhi(uA.x);
        a2 += wA * bflo(uA.y); a3 += wA * bfhi(uA.y);
        a0 += wB * bflo(uB.x); a1 += wB * bfhi(uB.x);
        a2 += wB * bflo(uB.y); a3 += wB * bfhi(uB.y);
    }
    for (; e + 4 <= e1; e += 4) {
        int c = col[e + g];
        float wv = rdeg[c];
        uint2 u = x1q[((size_t)c << 4) + hl];
        a0 += wv * bflo(u.x); a1 += wv * bfhi(u.x);
        a2 += wv * bflo(u.y); a3 += wv * bfhi(u.y);
    }
    if (e < e1) {
        int idx = e + g;
        if (idx < e1) {
            int c = col[idx];
            float wv = rdeg[c];
            uint2 u = x1q[((size_t)c << 4) + hl];
            a0 += wv * bflo(u.x); a1 += wv * bfhi(u.x);
            a2 += wv * bflo(u.y); a3 += wv * bfhi(u.y);
        }
    }
    a0 += __shfl_xor(a0, 16); a1 += __shfl_xor(a1, 16);
    a2 += __shfl_xor(a2, 16); a3 += __shfl_xor(a3, 16);
    a0 += __shfl_xor(a0, 32); a1 += __shfl_xor(a1, 32);
    a2 += __shfl_xor(a2, 32); a3 += __shfl_xor(a3, 32);
    float rd = rdeg[node];
    a0 *= rd; a1 *= rd; a2 *= rd; a3 *= rd;
    // self rows (broadcast across the 4 duplicated groups)
    uint2 u0 = x0q[((size_t)node << 4) + hl];
    uint2 u1 = x1q[((size_t)node << 4) + hl];
    float v0 = (bflo(u0.x) + bflo(u1.x) + a0) * (1.0f / 3.0f);
    float v1 = (bfhi(u0.x) + bfhi(u1.x) + a1) * (1.0f / 3.0f);
    float v2 = (bflo(u0.y) + bflo(u1.y) + a2) * (1.0f / 3.0f);
    float v3 = (bfhi(u0.y) + bfhi(u1.y) + a3) * (1.0f / 3.0f);
    // sum of squares over the 16-lane group (groups are duplicates)
    float ss = v0 * v0 + v1 * v1 + v2 * v2 + v3 * v3;
    #pragma unroll
    for (int off = 1; off < 16; off <<= 1) ss += __shfl_xor(ss, off);
    float theta = fmaxf(sqrtf(ss), 1e-7f);
    float sc = sinhf(theta) / theta;
    float* o = out + (long)node * 129;
    if (g == 0) {
        float4 v4 = make_float4(v0, v1, v2, v3);
        *(float4*)(o + 4 * hl) = v4;            // dims 0..63
        if (hl == 0) o[64] = coshf(theta);      // time coordinate
    } else if (g == 1) {
        float4 l4 = make_float4(sc * v0, sc * v1, sc * v2, sc * v3);
        *(float4*)(o + 65 + 4 * hl) = l4;       // lifted spatial part
    }
}

extern "C" void kernel_launch(void* const* d_in, const int* in_sizes, int n_in,
                              void* d_out, int out_size, void* d_ws, size_t ws_size,
                              hipStream_t stream) {
    const float* ue = (const float*)d_in[0];
    const float* ie = (const float*)d_in[1];
    const int*   hl = (const int*)d_in[2];
    const int*   tl = (const int*)d_in[3];
    float* out = (float*)d_out;

    const int n_users = in_sizes[0] / DIM;
    const int n_items = in_sizes[1] / DIM;
    const int N = n_users + n_items;
    const int E = in_sizes[2];
    const int nblocks_scan = (N + SCAN_ELEMS - 1) / SCAN_ELEMS;
    const int nb = (N + (1 << BSHIFT) - 1) >> BSHIFT;   // coarse buckets (<=MAXB)
    const long M = (long)N * DIM;

    // workspace layout (256B-aligned):
    // counts[N] | row_ptr[N+1] | cursor[N] | bsum | bcur | rdeg[N] | col[E]
    //   | tmp[E int2] | x0h[M u16] | x1h[M u16]
    auto align = [](size_t x) { return (x + 255) & ~(size_t)255; };
    char* p = (char*)d_ws;
    unsigned* counts  = (unsigned*)p;            p += align((size_t)N * 4);
    unsigned* row_ptr = (unsigned*)p;            p += align((size_t)(N + 1) * 4);
    unsigned* cursor  = (unsigned*)p;            p += align((size_t)N * 4);
    unsigned* bsum    = (unsigned*)p;            p += align((size_t)nblocks_scan * 4);
    unsigned* bcur    = (unsigned*)p;            p += align((size_t)MAXB * 4);
    float*    rdeg    = (float*)p;               p += align((size_t)N * 4);
    int*      col     = (int*)p;                 p += align((size_t)E * 4);
    int2*     tmp     = (int2*)p;                p += align((size_t)E * 8);
    unsigned short* x0h = (unsigned short*)p;    p += align((size_t)M * 2);
    unsigned short* x1h = (unsigned short*)p;    // M u16
    const uint2* x0q = (const uint2*)x0h;
    uint2* x1q = (uint2*)x1h;

    // 1) zero counts
    zero_u32<<<256, 256, 0, stream>>>(counts, N);

    // 2) degree histogram
    count_deg<<<(E + 255) / 256, 256, 0, stream>>>(hl, counts, E);

    // 2b) convert x0 -> bf16 table (independent of CSR build)
    {
        long threads = (M + 3) / 4;
        int blocks = (int)((threads + 255) / 256);
        cvt_x0<<<blocks, 256, 0, stream>>>(ue, ie, (long)n_users * DIM, x0h, M);
    }

    // 3) exclusive scan counts -> row_ptr (+ rdeg fused)
    block_reduce_counts<<<nblocks_scan, 256, 0, stream>>>(counts, bsum, N);
    scan_block_sums<<<1, 256, 0, stream>>>(bsum, nblocks_scan, row_ptr, N, E);
    scan_within_block<<<nblocks_scan, 256, 0, stream>>>(counts, bsum, row_ptr, rdeg, N);

    // 4) cursor = row_ptr[0..N); bcur = rp at bucket starts
    hipMemcpyAsync(cursor, row_ptr, (size_t)N * 4, hipMemcpyDeviceToDevice, stream);
    init_bcur<<<1, 256, 0, stream>>>(row_ptr, bcur, nb, N);

    // 5) coarse partition of (h,t) by h>>BSHIFT into tmp (CSR-shared index space)
    {
        int blocks = (E + CHUNK - 1) / CHUNK;
        partition_edges<<<blocks, 256, 0, stream>>>(hl, tl, bcur, tmp, E, nb);
    }

    // 6) fine scatter into CSR col (XCD-swizzled, L2-local windows)
    scatter_csr<<<(E + 255) / 256, 256, 0, stream>>>(tmp, cursor, col, E);

    // 7) layer 1: x1 = G @ x0 (pull, 4 edges/wave, u64 bf16x4 gathers)
    {
        int rows_per_block = 256 / 64;
        int blocks = (N + rows_per_block - 1) / rows_per_block;
        spmm_pull_l1<<<blocks, 256, 0, stream>>>(row_ptr, col, rdeg, x0q, x1q, N);
    }

    // 8) layer 2 + finalize fused
    {
        int rows_per_block = 256 / 64;
        int blocks = (N + rows_per_block - 1) / rows_per_block;
        spmm_l2_finalize<<<blocks, 256, 0, stream>>>(row_ptr, col, rdeg, x0q, x1q,
                                                     out, N);
    }
}

// Round 8
// 426.953 us; speedup vs baseline: 1.6816x; 1.6816x over previous
//
#include <hip/hip_runtime.h>

#define DIM 64
#define CHUNK 16384       // edges per partition block
#define BSHIFT 11         // 2048 nodes per coarse bucket
#define BSIZE (1 << BSHIFT)
#define MAXB 128          // max coarse buckets (N<=262144)

// ---- bf16 helpers (RNE) ----
__device__ __forceinline__ unsigned f2bf(float f) {
    unsigned u = __float_as_uint(f);
    return (u + 0x7FFFu + ((u >> 16) & 1u)) >> 16;
}
__device__ __forceinline__ float bflo(unsigned u) {   // low u16 -> f32
    return __uint_as_float(u << 16);
}
__device__ __forceinline__ float bfhi(unsigned u) {   // high u16 -> f32
    return __uint_as_float(u & 0xFFFF0000u);
}

// ---------------- zero u32 region ----------------
__global__ void zero_u32(unsigned* __restrict__ p, int n) {
    int i = blockIdx.x * blockDim.x + threadIdx.x;
    int stride = gridDim.x * blockDim.x;
    for (; i < n; i += stride) p[i] = 0u;
}

// ---------------- convert concat(ue,ie) f32 -> bf16 table ----------------
__global__ void cvt_x0(const float* __restrict__ ue, const float* __restrict__ ie,
                       long nu_elems, unsigned short* __restrict__ x0h, long M) {
    long i4 = ((long)blockIdx.x * blockDim.x + threadIdx.x) * 4;
    long stride = (long)gridDim.x * blockDim.x * 4;
    for (; i4 < M; i4 += stride) {
        const float* src = (i4 < nu_elems) ? ue + i4 : ie + (i4 - nu_elems);
        float4 v = *(const float4*)src;
        ushort4 o;
        o.x = (unsigned short)f2bf(v.x); o.y = (unsigned short)f2bf(v.y);
        o.z = (unsigned short)f2bf(v.z); o.w = (unsigned short)f2bf(v.w);
        *(ushort4*)(x0h + i4) = o;
    }
}

// ---------------- coarse bucket histogram (128 bins, LDS + global merge) ----------------
__global__ void bucket_hist(const int* __restrict__ h, unsigned* __restrict__ bcount,
                            int E, int nb) {
    __shared__ unsigned s[MAXB];
    for (int i = threadIdx.x; i < nb; i += blockDim.x) s[i] = 0u;
    __syncthreads();
    int i = blockIdx.x * blockDim.x + threadIdx.x;
    int stride = gridDim.x * blockDim.x;
    for (; i < E; i += stride) atomicAdd(&s[((unsigned)h[i]) >> BSHIFT], 1u);
    __syncthreads();
    for (int i = threadIdx.x; i < nb; i += blockDim.x)
        if (s[i]) atomicAdd(&bcount[i], s[i]);
}

// ---------------- scan bucket counts -> bbase/bcur (1 block of MAXB threads) ----------------
__global__ void bucket_scan(const unsigned* __restrict__ bcount,
                            unsigned* __restrict__ bbase, unsigned* __restrict__ bcur,
                            unsigned* __restrict__ row_ptr, int nb, int N, int E) {
    __shared__ unsigned s[MAXB];
    int tid = threadIdx.x;
    unsigned v = (tid < nb) ? bcount[tid] : 0u;
    s[tid] = v; __syncthreads();
    for (int off = 1; off < MAXB; off <<= 1) {
        unsigned t = (tid >= off) ? s[tid - off] : 0u;
        __syncthreads();
        s[tid] += t; __syncthreads();
    }
    if (tid < nb) {
        unsigned ex = s[tid] - v;   // exclusive
        bbase[tid] = ex;
        bcur[tid] = ex;
    }
    if (tid == 0) {
        bbase[nb] = (unsigned)E;
        row_ptr[N] = (unsigned)E;
    }
}

// ---------------- coarse partition: (h,t) pairs -> bucket-contiguous tmp ----------------
__global__ void partition_edges(const int* __restrict__ h, const int* __restrict__ t,
                                unsigned* __restrict__ bcur, int2* __restrict__ tmp,
                                int E, int nb) {
    __shared__ unsigned cnt[MAXB];
    int tid = threadIdx.x;
    long start = (long)blockIdx.x * CHUNK;
    long end = start + CHUNK; if (end > E) end = E;
    for (int i = tid; i < nb; i += blockDim.x) cnt[i] = 0u;
    __syncthreads();
    for (long i = start + tid; i < end; i += blockDim.x)
        atomicAdd(&cnt[((unsigned)h[i]) >> BSHIFT], 1u);
    __syncthreads();
    for (int i = tid; i < nb; i += blockDim.x) {
        unsigned c = cnt[i];
        cnt[i] = c ? atomicAdd(&bcur[i], c) : 0u;   // reserve chunk; cnt becomes cursor
    }
    __syncthreads();
    for (long i = start + tid; i < end; i += blockDim.x) {
        int hn = h[i], tn = t[i];
        unsigned pos = atomicAdd(&cnt[((unsigned)hn) >> BSHIFT], 1u);
        tmp[pos] = make_int2(hn, tn);
    }
}

// ---------------- per-bucket CSR build: LDS histogram + scan + LDS-atomic place ----------------
// One block per bucket. Writes row_ptr/rdeg for its 2048-node range and col for
// its edge region. No global atomics; col stores stay in a ~130KB L2 window.
__global__ void build_csr_bucket(const int2* __restrict__ tmp,
                                 const unsigned* __restrict__ bbase,
                                 unsigned* __restrict__ row_ptr,
                                 float* __restrict__ rdeg,
                                 int* __restrict__ col, int N) {
    __shared__ unsigned cnt[BSIZE];
    __shared__ unsigned cur[BSIZE];
    __shared__ unsigned ts[512];
    int b = blockIdx.x;
    int tid = threadIdx.x;
    unsigned e0 = bbase[b], e1 = bbase[b + 1];
    int nlo = b << BSHIFT;
    int nloc = N - nlo; if (nloc > BSIZE) nloc = BSIZE;
    for (int i = tid; i < nloc; i += 512) cnt[i] = 0u;
    __syncthreads();
    for (unsigned i = e0 + tid; i < e1; i += 512)
        atomicAdd(&cnt[tmp[i].x - nlo], 1u);
    __syncthreads();
    // exclusive scan over cnt[0..nloc): 512 threads x 4 elems
    int base = tid * 4;
    unsigned mysum = 0;
    #pragma unroll
    for (int j = 0; j < 4; ++j) { int i = base + j; if (i < nloc) mysum += cnt[i]; }
    ts[tid] = mysum; __syncthreads();
    for (int off = 1; off < 512; off <<= 1) {
        unsigned t = (tid >= off) ? ts[tid - off] : 0u;
        __syncthreads();
        ts[tid] += t; __syncthreads();
    }
    unsigned off0 = ts[tid] - mysum;
    #pragma unroll
    for (int j = 0; j < 4; ++j) {
        int i = base + j;
        if (i < nloc) {
            unsigned c = cnt[i];
            cur[i] = off0;
            row_ptr[nlo + i] = e0 + off0;
            rdeg[nlo + i] = rsqrtf(fmaxf((float)c, 1.0f));
            off0 += c;
        }
    }
    __syncthreads();
    for (unsigned i = e0 + tid; i < e1; i += 512) {
        int2 e = tmp[i];
        unsigned pos = e0 + atomicAdd(&cur[e.x - nlo], 1u);
        col[pos] = e.y;
    }
}

// ---------------- pull SpMM layer 1: x1 = G @ x0 ----------------
// Four edges per wave: 16-lane group g handles edge e+g; each lane loads one
// u64 (4 bf16 dims).
__global__ void spmm_pull_l1(const unsigned* __restrict__ rp,
                             const int* __restrict__ col,
                             const float* __restrict__ rdeg,
                             const uint2* __restrict__ x0q,
                             uint2* __restrict__ x1q, int N) {
    int node = blockIdx.x * (blockDim.x >> 6) + (threadIdx.x >> 6);
    int lane = threadIdx.x & 63;
    int g  = lane >> 4;     // edge slot 0..3
    int hl = lane & 15;     // dim quad 0..15
    if (node >= N) return;
    int e0 = __builtin_amdgcn_readfirstlane((int)rp[node]);
    int e1 = __builtin_amdgcn_readfirstlane((int)rp[node + 1]);
    float a0 = 0.f, a1 = 0.f, a2 = 0.f, a3 = 0.f;
    int e = e0;
    for (; e + 8 <= e1; e += 8) {     // 8 edges in flight
        int cA = col[e + g],     cB = col[e + 4 + g];
        float wA = rdeg[cA],     wB = rdeg[cB];
        uint2 uA = x0q[((size_t)cA << 4) + hl];
        uint2 uB = x0q[((size_t)cB << 4) + hl];
        a0 += wA * bflo(uA.x); a1 += wA * bfhi(uA.x);
        a2 += wA * bflo(uA.y); a3 += wA * bfhi(uA.y);
        a0 += wB * bflo(uB.x); a1 += wB * bfhi(uB.x);
        a2 += wB * bflo(uB.y); a3 += wB * bfhi(uB.y);
    }
    for (; e + 4 <= e1; e += 4) {
        int c = col[e + g];
        float wv = rdeg[c];
        uint2 u = x0q[((size_t)c << 4) + hl];
        a0 += wv * bflo(u.x); a1 += wv * bfhi(u.x);
        a2 += wv * bflo(u.y); a3 += wv * bfhi(u.y);
    }
    if (e < e1) {                     // masked tail: 1..3 edges
        int idx = e + g;
        if (idx < e1) {
            int c = col[idx];
            float wv = rdeg[c];
            uint2 u = x0q[((size_t)c << 4) + hl];
            a0 += wv * bflo(u.x); a1 += wv * bfhi(u.x);
            a2 += wv * bflo(u.y); a3 += wv * bfhi(u.y);
        }
    }
    a0 += __shfl_xor(a0, 16); a1 += __shfl_xor(a1, 16);
    a2 += __shfl_xor(a2, 16); a3 += __shfl_xor(a3, 16);
    a0 += __shfl_xor(a0, 32); a1 += __shfl_xor(a1, 32);
    a2 += __shfl_xor(a2, 32); a3 += __shfl_xor(a3, 32);
    if (g == 0) {
        float rd = rdeg[node];
        uint2 o;
        o.x = (f2bf(rd * a1) << 16) | f2bf(rd * a0);
        o.y = (f2bf(rd * a3) << 16) | f2bf(rd * a2);
        x1q[((size_t)node << 4) + hl] = o;
    }
}

// ---------------- pull SpMM layer 2 fused with finalize ----------------
__global__ void spmm_l2_finalize(const unsigned* __restrict__ rp,
                                 const int* __restrict__ col,
                                 const float* __restrict__ rdeg,
                                 const uint2* __restrict__ x0q,
                                 const uint2* __restrict__ x1q,
                                 float* __restrict__ out, int N) {
    int node = blockIdx.x * (blockDim.x >> 6) + (threadIdx.x >> 6);
    int lane = threadIdx.x & 63;
    int g  = lane >> 4;
    int hl = lane & 15;
    if (node >= N) return;
    int e0 = __builtin_amdgcn_readfirstlane((int)rp[node]);
    int e1 = __builtin_amdgcn_readfirstlane((int)rp[node + 1]);
    float a0 = 0.f, a1 = 0.f, a2 = 0.f, a3 = 0.f;
    int e = e0;
    for (; e + 8 <= e1; e += 8) {
        int cA = col[e + g],     cB = col[e + 4 + g];
        float wA = rdeg[cA],     wB = rdeg[cB];
        uint2 uA = x1q[((size_t)cA << 4) + hl];
        uint2 uB = x1q[((size_t)cB << 4) + hl];
        a0 += wA * bflo(uA.x); a1 += wA * bfhi(uA.x);
        a2 += wA * bflo(uA.y); a3 += wA * bfhi(uA.y);
        a0 += wB * bflo(uB.x); a1 += wB * bfhi(uB.x);
        a2 += wB * bflo(uB.y); a3 += wB * bfhi(uB.y);
    }
    for (; e + 4 <= e1; e += 4) {
        int c = col[e + g];
        float wv = rdeg[c];
        uint2 u = x1q[((size_t)c << 4) + hl];
        a0 += wv * bflo(u.x); a1 += wv * bfhi(u.x);
        a2 += wv * bflo(u.y); a3 += wv * bfhi(u.y);
    }
    if (e < e1) {
        int idx = e + g;
        if (idx < e1) {
            int c = col[idx];
            float wv = rdeg[c];
            uint2 u = x1q[((size_t)c << 4) + hl];
            a0 += wv * bflo(u.x); a1 += wv * bfhi(u.x);
            a2 += wv * bflo(u.y); a3 += wv * bfhi(u.y);
        }
    }
    a0 += __shfl_xor(a0, 16); a1 += __shfl_xor(a1, 16);
    a2 += __shfl_xor(a2, 16); a3 += __shfl_xor(a3, 16);
    a0 += __shfl_xor(a0, 32); a1 += __shfl_xor(a1, 32);
    a2 += __shfl_xor(a2, 32); a3 += __shfl_xor(a3, 32);
    float rd = rdeg[node];
    a0 *= rd; a1 *= rd; a2 *= rd; a3 *= rd;
    uint2 u0 = x0q[((size_t)node << 4) + hl];
    uint2 u1 = x1q[((size_t)node << 4) + hl];
    float v0 = (bflo(u0.x) + bflo(u1.x) + a0) * (1.0f / 3.0f);
    float v1 = (bfhi(u0.x) + bfhi(u1.x) + a1) * (1.0f / 3.0f);
    float v2 = (bflo(u0.y) + bflo(u1.y) + a2) * (1.0f / 3.0f);
    float v3 = (bfhi(u0.y) + bfhi(u1.y) + a3) * (1.0f / 3.0f);
    float ss = v0 * v0 + v1 * v1 + v2 * v2 + v3 * v3;
    #pragma unroll
    for (int off = 1; off < 16; off <<= 1) ss += __shfl_xor(ss, off);
    float theta = fmaxf(sqrtf(ss), 1e-7f);
    float sc = sinhf(theta) / theta;
    float* o = out + (long)node * 129;
    if (g == 0) {
        float4 v4 = make_float4(v0, v1, v2, v3);
        *(float4*)(o + 4 * hl) = v4;            // dims 0..63
        if (hl == 0) o[64] = coshf(theta);      // time coordinate
    } else if (g == 1) {
        float4 l4 = make_float4(sc * v0, sc * v1, sc * v2, sc * v3);
        *(float4*)(o + 65 + 4 * hl) = l4;       // lifted spatial part
    }
}

extern "C" void kernel_launch(void* const* d_in, const int* in_sizes, int n_in,
                              void* d_out, int out_size, void* d_ws, size_t ws_size,
                              hipStream_t stream) {
    const float* ue = (const float*)d_in[0];
    const float* ie = (const float*)d_in[1];
    const int*   hl = (const int*)d_in[2];
    const int*   tl = (const int*)d_in[3];
    float* out = (float*)d_out;

    const int n_users = in_sizes[0] / DIM;
    const int n_items = in_sizes[1] / DIM;
    const int N = n_users + n_items;
    const int E = in_sizes[2];
    const int nb = (N + BSIZE - 1) >> BSHIFT;   // coarse buckets (<=MAXB)
    const long M = (long)N * DIM;

    // workspace layout (256B-aligned):
    // row_ptr[N+1] | rdeg[N] | bcount[MAXB] | bbase[MAXB+1] | bcur[MAXB]
    //   | col[E] | tmp[E int2] | x0h[M u16] | x1h[M u16]
    auto align = [](size_t x) { return (x + 255) & ~(size_t)255; };
    char* p = (char*)d_ws;
    unsigned* row_ptr = (unsigned*)p;            p += align((size_t)(N + 1) * 4);
    float*    rdeg    = (float*)p;               p += align((size_t)N * 4);
    unsigned* bcount  = (unsigned*)p;            p += align((size_t)MAXB * 4);
    unsigned* bbase   = (unsigned*)p;            p += align((size_t)(MAXB + 1) * 4);
    unsigned* bcur    = (unsigned*)p;            p += align((size_t)MAXB * 4);
    int*      col     = (int*)p;                 p += align((size_t)E * 4);
    int2*     tmp     = (int2*)p;                p += align((size_t)E * 8);
    unsigned short* x0h = (unsigned short*)p;    p += align((size_t)M * 2);
    unsigned short* x1h = (unsigned short*)p;    // M u16
    const uint2* x0q = (const uint2*)x0h;
    uint2* x1q = (uint2*)x1h;

    // 1) zero bucket counts
    zero_u32<<<1, 256, 0, stream>>>(bcount, MAXB);

    // 2) coarse bucket histogram
    bucket_hist<<<512, 256, 0, stream>>>(hl, bcount, E, nb);

    // 2b) convert x0 -> bf16 table (independent of CSR build)
    {
        long threads = (M + 3) / 4;
        int blocks = (int)((threads + 255) / 256);
        cvt_x0<<<blocks, 256, 0, stream>>>(ue, ie, (long)n_users * DIM, x0h, M);
    }

    // 3) scan bucket counts -> bbase/bcur; row_ptr[N]=E
    bucket_scan<<<1, MAXB, 0, stream>>>(bcount, bbase, bcur, row_ptr, nb, N, E);

    // 4) coarse partition of (h,t) by h>>BSHIFT into tmp
    {
        int blocks = (E + CHUNK - 1) / CHUNK;
        partition_edges<<<blocks, 256, 0, stream>>>(hl, tl, bcur, tmp, E, nb);
    }

    // 5) per-bucket CSR build (row_ptr, rdeg, col) — LDS atomics only
    build_csr_bucket<<<nb, 512, 0, stream>>>(tmp, bbase, row_ptr, rdeg, col, N);

    // 6) layer 1: x1 = G @ x0 (pull, 4 edges/wave, u64 bf16x4 gathers)
    {
        int rows_per_block = 256 / 64;
        int blocks = (N + rows_per_block - 1) / rows_per_block;
        spmm_pull_l1<<<blocks, 256, 0, stream>>>(row_ptr, col, rdeg, x0q, x1q, N);
    }

    // 7) layer 2 + finalize fused
    {
        int rows_per_block = 256 / 64;
        int blocks = (N + rows_per_block - 1) / rows_per_block;
        spmm_l2_finalize<<<blocks, 256, 0, stream>>>(row_ptr, col, rdeg, x0q, x1q,
                                                     out, N);
    }
}

// Round 9
// 408.939 us; speedup vs baseline: 1.7557x; 1.0441x over previous
//
#include <hip/hip_runtime.h>

#define DIM 64
#define CHUNK 16384       // edges per partition block
#define BSHIFT 11         // 2048 nodes per coarse bucket
#define BSIZE (1 << BSHIFT)
#define MAXB 128          // max coarse buckets (N<=262144)

// ---- bf16 helpers (RNE) ----
__device__ __forceinline__ unsigned f2bf(float f) {
    unsigned u = __float_as_uint(f);
    return (u + 0x7FFFu + ((u >> 16) & 1u)) >> 16;
}
__device__ __forceinline__ float bflo(unsigned u) {   // low u16 -> f32
    return __uint_as_float(u << 16);
}
__device__ __forceinline__ float bfhi(unsigned u) {   // high u16 -> f32
    return __uint_as_float(u & 0xFFFF0000u);
}

// ---------------- zero u32 region ----------------
__global__ void zero_u32(unsigned* __restrict__ p, int n) {
    int i = blockIdx.x * blockDim.x + threadIdx.x;
    int stride = gridDim.x * blockDim.x;
    for (; i < n; i += stride) p[i] = 0u;
}

// ---------------- coarse bucket histogram (128 bins, LDS + global merge) ----------------
__global__ void bucket_hist(const int* __restrict__ h, unsigned* __restrict__ bcount,
                            int E, int nb) {
    __shared__ unsigned s[MAXB];
    for (int i = threadIdx.x; i < nb; i += blockDim.x) s[i] = 0u;
    __syncthreads();
    int i = blockIdx.x * blockDim.x + threadIdx.x;
    int stride = gridDim.x * blockDim.x;
    for (; i < E; i += stride) atomicAdd(&s[((unsigned)h[i]) >> BSHIFT], 1u);
    __syncthreads();
    for (int i = threadIdx.x; i < nb; i += blockDim.x)
        if (s[i]) atomicAdd(&bcount[i], s[i]);
}

// ---------------- scan bucket counts -> bbase/bcur (1 block of MAXB threads) ----------------
__global__ void bucket_scan(const unsigned* __restrict__ bcount,
                            unsigned* __restrict__ bbase, unsigned* __restrict__ bcur,
                            unsigned* __restrict__ row_ptr, int nb, int N, int E) {
    __shared__ unsigned s[MAXB];
    int tid = threadIdx.x;
    unsigned v = (tid < nb) ? bcount[tid] : 0u;
    s[tid] = v; __syncthreads();
    for (int off = 1; off < MAXB; off <<= 1) {
        unsigned t = (tid >= off) ? s[tid - off] : 0u;
        __syncthreads();
        s[tid] += t; __syncthreads();
    }
    if (tid < nb) {
        unsigned ex = s[tid] - v;   // exclusive
        bbase[tid] = ex;
        bcur[tid] = ex;
    }
    if (tid == 0) {
        bbase[nb] = (unsigned)E;
        row_ptr[N] = (unsigned)E;
    }
}

// ---------------- coarse partition: (h,t) pairs -> bucket-contiguous tmp ----------------
__global__ void partition_edges(const int* __restrict__ h, const int* __restrict__ t,
                                unsigned* __restrict__ bcur, int2* __restrict__ tmp,
                                int E, int nb) {
    __shared__ unsigned cnt[MAXB];
    int tid = threadIdx.x;
    long start = (long)blockIdx.x * CHUNK;
    long end = start + CHUNK; if (end > E) end = E;
    for (int i = tid; i < nb; i += blockDim.x) cnt[i] = 0u;
    __syncthreads();
    for (long i = start + tid; i < end; i += blockDim.x)
        atomicAdd(&cnt[((unsigned)h[i]) >> BSHIFT], 1u);
    __syncthreads();
    for (int i = tid; i < nb; i += blockDim.x) {
        unsigned c = cnt[i];
        cnt[i] = c ? atomicAdd(&bcur[i], c) : 0u;   // reserve chunk; cnt becomes cursor
    }
    __syncthreads();
    for (long i = start + tid; i < end; i += blockDim.x) {
        int hn = h[i], tn = t[i];
        unsigned pos = atomicAdd(&cnt[((unsigned)hn) >> BSHIFT], 1u);
        tmp[pos] = make_int2(hn, tn);
    }
}

// ---------------- per-bucket CSR build: LDS histogram + scan + LDS-atomic place ----------------
// One block per bucket; writes row_ptr/rdeg/rsq for its node range + col region.
__global__ void build_csr_bucket(const int2* __restrict__ tmp,
                                 const unsigned* __restrict__ bbase,
                                 unsigned* __restrict__ row_ptr,
                                 float* __restrict__ rdeg,
                                 float* __restrict__ rsq,
                                 int* __restrict__ col, int N) {
    __shared__ unsigned cnt[BSIZE];
    __shared__ unsigned cur[BSIZE];
    __shared__ unsigned ts[512];
    int b = blockIdx.x;
    int tid = threadIdx.x;
    unsigned e0 = bbase[b], e1 = bbase[b + 1];
    int nlo = b << BSHIFT;
    int nloc = N - nlo; if (nloc > BSIZE) nloc = BSIZE;
    for (int i = tid; i < nloc; i += 512) cnt[i] = 0u;
    __syncthreads();
    for (unsigned i = e0 + tid; i < e1; i += 512)
        atomicAdd(&cnt[tmp[i].x - nlo], 1u);
    __syncthreads();
    // exclusive scan over cnt[0..nloc): 512 threads x 4 elems
    int base = tid * 4;
    unsigned mysum = 0;
    #pragma unroll
    for (int j = 0; j < 4; ++j) { int i = base + j; if (i < nloc) mysum += cnt[i]; }
    ts[tid] = mysum; __syncthreads();
    for (int off = 1; off < 512; off <<= 1) {
        unsigned t = (tid >= off) ? ts[tid - off] : 0u;
        __syncthreads();
        ts[tid] += t; __syncthreads();
    }
    unsigned off0 = ts[tid] - mysum;
    #pragma unroll
    for (int j = 0; j < 4; ++j) {
        int i = base + j;
        if (i < nloc) {
            unsigned c = cnt[i];
            float d = fmaxf((float)c, 1.0f);
            cur[i] = off0;
            row_ptr[nlo + i] = e0 + off0;
            rdeg[nlo + i] = rsqrtf(d);
            rsq[nlo + i]  = sqrtf(d);
            off0 += c;
        }
    }
    __syncthreads();
    for (unsigned i = e0 + tid; i < e1; i += 512) {
        int2 e = tmp[i];
        unsigned pos = e0 + atomicAdd(&cur[e.x - nlo], 1u);
        col[pos] = e.y;
    }
}

// ---------------- convert concat(ue,ie) f32 -> PRE-SCALED bf16 table ----------------
// x0s[n][d] = rdeg[n] * x0[n][d]  (bf16 RNE). 16 threads/row, 4 elems/thread.
__global__ void cvt_x0s(const float* __restrict__ ue, const float* __restrict__ ie,
                        long nu_elems, const float* __restrict__ rdeg,
                        unsigned short* __restrict__ x0s, long M) {
    long i4 = ((long)blockIdx.x * blockDim.x + threadIdx.x) * 4;
    long stride = (long)gridDim.x * blockDim.x * 4;
    for (; i4 < M; i4 += stride) {
        const float* src = (i4 < nu_elems) ? ue + i4 : ie + (i4 - nu_elems);
        float rd = rdeg[i4 >> 6];
        float4 v = *(const float4*)src;
        ushort4 o;
        o.x = (unsigned short)f2bf(rd * v.x); o.y = (unsigned short)f2bf(rd * v.y);
        o.z = (unsigned short)f2bf(rd * v.z); o.w = (unsigned short)f2bf(rd * v.w);
        *(ushort4*)(x0s + i4) = o;
    }
}

// ---------------- pull SpMM layer 1: x1s = rdeg^2 * (sum of x0s rows) ----------------
// Four edges per wave (16 lanes/edge, uint2 = 4 bf16 dims/lane). Pre-scaled
// table -> inner loop is pure gather+add (no weight load, no FMA dependency).
__global__ void spmm_pull_l1(const unsigned* __restrict__ rp,
                             const int* __restrict__ col,
                             const float* __restrict__ rdeg,
                             const uint2* __restrict__ x0s,
                             uint2* __restrict__ x1s, int N) {
    int node = blockIdx.x * (blockDim.x >> 6) + (threadIdx.x >> 6);
    int lane = threadIdx.x & 63;
    int g  = lane >> 4;     // edge slot 0..3
    int hl = lane & 15;     // dim quad 0..15
    if (node >= N) return;
    int e0 = __builtin_amdgcn_readfirstlane((int)rp[node]);
    int e1 = __builtin_amdgcn_readfirstlane((int)rp[node + 1]);
    float a0 = 0.f, a1 = 0.f, a2 = 0.f, a3 = 0.f;
    int e = e0;
    for (; e + 8 <= e1; e += 8) {     // 8 edges in flight
        int cA = col[e + g], cB = col[e + 4 + g];
        uint2 uA = x0s[((size_t)cA << 4) + hl];
        uint2 uB = x0s[((size_t)cB << 4) + hl];
        a0 += bflo(uA.x); a1 += bfhi(uA.x);
        a2 += bflo(uA.y); a3 += bfhi(uA.y);
        a0 += bflo(uB.x); a1 += bfhi(uB.x);
        a2 += bflo(uB.y); a3 += bfhi(uB.y);
    }
    for (; e + 4 <= e1; e += 4) {
        int c = col[e + g];
        uint2 u = x0s[((size_t)c << 4) + hl];
        a0 += bflo(u.x); a1 += bfhi(u.x);
        a2 += bflo(u.y); a3 += bfhi(u.y);
    }
    if (e < e1) {                     // masked tail: 1..3 edges
        int idx = e + g;
        if (idx < e1) {
            int c = col[idx];
            uint2 u = x0s[((size_t)c << 4) + hl];
            a0 += bflo(u.x); a1 += bfhi(u.x);
            a2 += bflo(u.y); a3 += bfhi(u.y);
        }
    }
    a0 += __shfl_xor(a0, 16); a1 += __shfl_xor(a1, 16);
    a2 += __shfl_xor(a2, 16); a3 += __shfl_xor(a3, 16);
    a0 += __shfl_xor(a0, 32); a1 += __shfl_xor(a1, 32);
    a2 += __shfl_xor(a2, 32); a3 += __shfl_xor(a3, 32);
    if (g == 0) {
        float rd = rdeg[node];
        float rd2 = rd * rd;          // x1s = rdeg * x1 = rdeg^2 * sum
        uint2 o;
        o.x = (f2bf(rd2 * a1) << 16) | f2bf(rd2 * a0);
        o.y = (f2bf(rd2 * a3) << 16) | f2bf(rd2 * a2);
        x1s[((size_t)node << 4) + hl] = o;
    }
}

// ---------------- pull SpMM layer 2 fused with finalize ----------------
__global__ void spmm_l2_finalize(const unsigned* __restrict__ rp,
                                 const int* __restrict__ col,
                                 const float* __restrict__ rdeg,
                                 const float* __restrict__ rsq,
                                 const uint2* __restrict__ x0s,
                                 const uint2* __restrict__ x1s,
                                 float* __restrict__ out, int N) {
    int node = blockIdx.x * (blockDim.x >> 6) + (threadIdx.x >> 6);
    int lane = threadIdx.x & 63;
    int g  = lane >> 4;
    int hl = lane & 15;
    if (node >= N) return;
    int e0 = __builtin_amdgcn_readfirstlane((int)rp[node]);
    int e1 = __builtin_amdgcn_readfirstlane((int)rp[node + 1]);
    float a0 = 0.f, a1 = 0.f, a2 = 0.f, a3 = 0.f;
    int e = e0;
    for (; e + 8 <= e1; e += 8) {
        int cA = col[e + g], cB = col[e + 4 + g];
        uint2 uA = x1s[((size_t)cA << 4) + hl];
        uint2 uB = x1s[((size_t)cB << 4) + hl];
        a0 += bflo(uA.x); a1 += bfhi(uA.x);
        a2 += bflo(uA.y); a3 += bfhi(uA.y);
        a0 += bflo(uB.x); a1 += bfhi(uB.x);
        a2 += bflo(uB.y); a3 += bfhi(uB.y);
    }
    for (; e + 4 <= e1; e += 4) {
        int c = col[e + g];
        uint2 u = x1s[((size_t)c << 4) + hl];
        a0 += bflo(u.x); a1 += bfhi(u.x);
        a2 += bflo(u.y); a3 += bfhi(u.y);
    }
    if (e < e1) {
        int idx = e + g;
        if (idx < e1) {
            int c = col[idx];
            uint2 u = x1s[((size_t)c << 4) + hl];
            a0 += bflo(u.x); a1 += bfhi(u.x);
            a2 += bflo(u.y); a3 += bfhi(u.y);
        }
    }
    a0 += __shfl_xor(a0, 16); a1 += __shfl_xor(a1, 16);
    a2 += __shfl_xor(a2, 16); a3 += __shfl_xor(a3, 16);
    a0 += __shfl_xor(a0, 32); a1 += __shfl_xor(a1, 32);
    a2 += __shfl_xor(a2, 32); a3 += __shfl_xor(a3, 32);
    float rd = rdeg[node];
    a0 *= rd; a1 *= rd; a2 *= rd; a3 *= rd;     // x2 = rdeg * sum(x1s)
    // self terms: x0 = x0s*rsq, x1 = x1s*rsq
    float rq = rsq[node];
    uint2 u0 = x0s[((size_t)node << 4) + hl];
    uint2 u1 = x1s[((size_t)node << 4) + hl];
    float v0 = (rq * (bflo(u0.x) + bflo(u1.x)) + a0) * (1.0f / 3.0f);
    float v1 = (rq * (bfhi(u0.x) + bfhi(u1.x)) + a1) * (1.0f / 3.0f);
    float v2 = (rq * (bflo(u0.y) + bflo(u1.y)) + a2) * (1.0f / 3.0f);
    float v3 = (rq * (bfhi(u0.y) + bfhi(u1.y)) + a3) * (1.0f / 3.0f);
    float ss = v0 * v0 + v1 * v1 + v2 * v2 + v3 * v3;
    #pragma unroll
    for (int off = 1; off < 16; off <<= 1) ss += __shfl_xor(ss, off);
    float theta = fmaxf(sqrtf(ss), 1e-7f);
    // hand-coded sinh/cosh: ~8 instrs vs sinhf+coshf library sequences
    float ex  = __expf(theta);
    float exi = __builtin_amdgcn_rcpf(ex);
    float sh = 0.5f * (ex - exi);
    float ch = 0.5f * (ex + exi);
    float sc = sh * __builtin_amdgcn_rcpf(theta);
    float* o = out + (long)node * 129;
    if (g == 0) {
        float4 v4 = make_float4(v0, v1, v2, v3);
        *(float4*)(o + 4 * hl) = v4;            // dims 0..63
        if (hl == 0) o[64] = ch;                // time coordinate
    } else if (g == 1) {
        float4 l4 = make_float4(sc * v0, sc * v1, sc * v2, sc * v3);
        *(float4*)(o + 65 + 4 * hl) = l4;       // lifted spatial part
    }
}

extern "C" void kernel_launch(void* const* d_in, const int* in_sizes, int n_in,
                              void* d_out, int out_size, void* d_ws, size_t ws_size,
                              hipStream_t stream) {
    const float* ue = (const float*)d_in[0];
    const float* ie = (const float*)d_in[1];
    const int*   hl = (const int*)d_in[2];
    const int*   tl = (const int*)d_in[3];
    float* out = (float*)d_out;

    const int n_users = in_sizes[0] / DIM;
    const int n_items = in_sizes[1] / DIM;
    const int N = n_users + n_items;
    const int E = in_sizes[2];
    const int nb = (N + BSIZE - 1) >> BSHIFT;   // coarse buckets (<=MAXB)
    const long M = (long)N * DIM;

    // workspace layout (256B-aligned):
    // row_ptr[N+1] | rdeg[N] | rsq[N] | bcount | bbase | bcur
    //   | col[E] | tmp[E int2] | x0s[M u16] | x1s[M u16]
    auto align = [](size_t x) { return (x + 255) & ~(size_t)255; };
    char* p = (char*)d_ws;
    unsigned* row_ptr = (unsigned*)p;            p += align((size_t)(N + 1) * 4);
    float*    rdeg    = (float*)p;               p += align((size_t)N * 4);
    float*    rsq     = (float*)p;               p += align((size_t)N * 4);
    unsigned* bcount  = (unsigned*)p;            p += align((size_t)MAXB * 4);
    unsigned* bbase   = (unsigned*)p;            p += align((size_t)(MAXB + 1) * 4);
    unsigned* bcur    = (unsigned*)p;            p += align((size_t)MAXB * 4);
    int*      col     = (int*)p;                 p += align((size_t)E * 4);
    int2*     tmp     = (int2*)p;                p += align((size_t)E * 8);
    unsigned short* x0sh = (unsigned short*)p;   p += align((size_t)M * 2);
    unsigned short* x1sh = (unsigned short*)p;   // M u16
    const uint2* x0s = (const uint2*)x0sh;
    uint2* x1s = (uint2*)x1sh;

    // 1) zero bucket counts
    zero_u32<<<1, 256, 0, stream>>>(bcount, MAXB);

    // 2) coarse bucket histogram
    bucket_hist<<<512, 256, 0, stream>>>(hl, bcount, E, nb);

    // 3) scan bucket counts -> bbase/bcur; row_ptr[N]=E
    bucket_scan<<<1, MAXB, 0, stream>>>(bcount, bbase, bcur, row_ptr, nb, N, E);

    // 4) coarse partition of (h,t) by h>>BSHIFT into tmp
    {
        int blocks = (E + CHUNK - 1) / CHUNK;
        partition_edges<<<blocks, 256, 0, stream>>>(hl, tl, bcur, tmp, E, nb);
    }

    // 5) per-bucket CSR build (row_ptr, rdeg, rsq, col) — LDS atomics only
    build_csr_bucket<<<nb, 512, 0, stream>>>(tmp, bbase, row_ptr, rdeg, rsq, col, N);

    // 6) pre-scaled bf16 table x0s = rdeg * x0 (needs rdeg -> after CSR build)
    {
        long threads = (M + 3) / 4;
        int blocks = (int)((threads + 255) / 256);
        cvt_x0s<<<blocks, 256, 0, stream>>>(ue, ie, (long)n_users * DIM, rdeg, x0sh, M);
    }

    // 7) layer 1: x1s = rdeg^2 * sum(x0s) (pull, pure gather+add)
    {
        int rows_per_block = 256 / 64;
        int blocks = (N + rows_per_block - 1) / rows_per_block;
        spmm_pull_l1<<<blocks, 256, 0, stream>>>(row_ptr, col, rdeg, x0s, x1s, N);
    }

    // 8) layer 2 + finalize fused
    {
        int rows_per_block = 256 / 64;
        int blocks = (N + rows_per_block - 1) / rows_per_block;
        spmm_l2_finalize<<<blocks, 256, 0, stream>>>(row_ptr, col, rdeg, rsq,
                                                     x0s, x1s, out, N);
    }
}

// Round 10
// 349.851 us; speedup vs baseline: 2.0522x; 1.1689x over previous
//
#include <hip/hip_runtime.h>

#define DIM 64
#define CHUNK 16384       // edges per partition block
#define BSHIFT 11         // 2048 nodes per coarse bucket
#define BSIZE (1 << BSHIFT)
#define MAXB 128          // max coarse buckets (N<=262144)

// ---- bf16 helpers (RNE) ----
__device__ __forceinline__ unsigned f2bf(float f) {
    unsigned u = __float_as_uint(f);
    return (u + 0x7FFFu + ((u >> 16) & 1u)) >> 16;
}
__device__ __forceinline__ float bflo(unsigned u) {   // low u16 -> f32
    return __uint_as_float(u << 16);
}
__device__ __forceinline__ float bfhi(unsigned u) {   // high u16 -> f32
    return __uint_as_float(u & 0xFFFF0000u);
}

// ---------------- zero u32 region ----------------
__global__ void zero_u32(unsigned* __restrict__ p, int n) {
    int i = blockIdx.x * blockDim.x + threadIdx.x;
    int stride = gridDim.x * blockDim.x;
    for (; i < n; i += stride) p[i] = 0u;
}

// ---------------- coarse bucket histogram (128 bins, LDS + global merge) ----------------
__global__ void bucket_hist(const int* __restrict__ h, unsigned* __restrict__ bcount,
                            int E, int nb) {
    __shared__ unsigned s[MAXB];
    for (int i = threadIdx.x; i < nb; i += blockDim.x) s[i] = 0u;
    __syncthreads();
    int i = blockIdx.x * blockDim.x + threadIdx.x;
    int stride = gridDim.x * blockDim.x;
    for (; i < E; i += stride) atomicAdd(&s[((unsigned)h[i]) >> BSHIFT], 1u);
    __syncthreads();
    for (int i = threadIdx.x; i < nb; i += blockDim.x)
        if (s[i]) atomicAdd(&bcount[i], s[i]);
}

// ---------------- scan bucket counts -> bbase/bcur (1 block of MAXB threads) ----------------
__global__ void bucket_scan(const unsigned* __restrict__ bcount,
                            unsigned* __restrict__ bbase, unsigned* __restrict__ bcur,
                            unsigned* __restrict__ row_ptr, int nb, int N, int E) {
    __shared__ unsigned s[MAXB];
    int tid = threadIdx.x;
    unsigned v = (tid < nb) ? bcount[tid] : 0u;
    s[tid] = v; __syncthreads();
    for (int off = 1; off < MAXB; off <<= 1) {
        unsigned t = (tid >= off) ? s[tid - off] : 0u;
        __syncthreads();
        s[tid] += t; __syncthreads();
    }
    if (tid < nb) {
        unsigned ex = s[tid] - v;   // exclusive
        bbase[tid] = ex;
        bcur[tid] = ex;
    }
    if (tid == 0) {
        bbase[nb] = (unsigned)E;
        row_ptr[N] = (unsigned)E;
    }
}

// ---------------- coarse partition: (h,t) pairs -> bucket-contiguous tmp ----------------
__global__ void partition_edges(const int* __restrict__ h, const int* __restrict__ t,
                                unsigned* __restrict__ bcur, int2* __restrict__ tmp,
                                int E, int nb) {
    __shared__ unsigned cnt[MAXB];
    int tid = threadIdx.x;
    long start = (long)blockIdx.x * CHUNK;
    long end = start + CHUNK; if (end > E) end = E;
    for (int i = tid; i < nb; i += blockDim.x) cnt[i] = 0u;
    __syncthreads();
    for (long i = start + tid; i < end; i += blockDim.x)
        atomicAdd(&cnt[((unsigned)h[i]) >> BSHIFT], 1u);
    __syncthreads();
    for (int i = tid; i < nb; i += blockDim.x) {
        unsigned c = cnt[i];
        cnt[i] = c ? atomicAdd(&bcur[i], c) : 0u;   // reserve chunk; cnt becomes cursor
    }
    __syncthreads();
    for (long i = start + tid; i < end; i += blockDim.x) {
        int hn = h[i], tn = t[i];
        unsigned pos = atomicAdd(&cnt[((unsigned)hn) >> BSHIFT], 1u);
        tmp[pos] = make_int2(hn, tn);
    }
}

// ---------------- per-bucket CSR build: LDS histogram + scan + LDS-atomic place ----------------
__global__ void build_csr_bucket(const int2* __restrict__ tmp,
                                 const unsigned* __restrict__ bbase,
                                 unsigned* __restrict__ row_ptr,
                                 float* __restrict__ rdeg,
                                 float* __restrict__ rsq,
                                 int* __restrict__ col, int N) {
    __shared__ unsigned cnt[BSIZE];
    __shared__ unsigned cur[BSIZE];
    __shared__ unsigned ts[512];
    int b = blockIdx.x;
    int tid = threadIdx.x;
    unsigned e0 = bbase[b], e1 = bbase[b + 1];
    int nlo = b << BSHIFT;
    int nloc = N - nlo; if (nloc > BSIZE) nloc = BSIZE;
    for (int i = tid; i < nloc; i += 512) cnt[i] = 0u;
    __syncthreads();
    for (unsigned i = e0 + tid; i < e1; i += 512)
        atomicAdd(&cnt[tmp[i].x - nlo], 1u);
    __syncthreads();
    // exclusive scan over cnt[0..nloc): 512 threads x 4 elems
    int base = tid * 4;
    unsigned mysum = 0;
    #pragma unroll
    for (int j = 0; j < 4; ++j) { int i = base + j; if (i < nloc) mysum += cnt[i]; }
    ts[tid] = mysum; __syncthreads();
    for (int off = 1; off < 512; off <<= 1) {
        unsigned t = (tid >= off) ? ts[tid - off] : 0u;
        __syncthreads();
        ts[tid] += t; __syncthreads();
    }
    unsigned off0 = ts[tid] - mysum;
    #pragma unroll
    for (int j = 0; j < 4; ++j) {
        int i = base + j;
        if (i < nloc) {
            unsigned c = cnt[i];
            float d = fmaxf((float)c, 1.0f);
            cur[i] = off0;
            row_ptr[nlo + i] = e0 + off0;
            rdeg[nlo + i] = rsqrtf(d);
            rsq[nlo + i]  = sqrtf(d);
            off0 += c;
        }
    }
    __syncthreads();
    for (unsigned i = e0 + tid; i < e1; i += 512) {
        int2 e = tmp[i];
        unsigned pos = e0 + atomicAdd(&cur[e.x - nlo], 1u);
        col[pos] = e.y;
    }
}

// ---------------- convert concat(ue,ie) f32 -> PRE-SCALED bf16 table ----------------
__global__ void cvt_x0s(const float* __restrict__ ue, const float* __restrict__ ie,
                        long nu_elems, const float* __restrict__ rdeg,
                        unsigned short* __restrict__ x0s, long M) {
    long i4 = ((long)blockIdx.x * blockDim.x + threadIdx.x) * 4;
    long stride = (long)gridDim.x * blockDim.x * 4;
    for (; i4 < M; i4 += stride) {
        const float* src = (i4 < nu_elems) ? ue + i4 : ie + (i4 - nu_elems);
        float rd = rdeg[i4 >> 6];
        float4 v = *(const float4*)src;
        ushort4 o;
        o.x = (unsigned short)f2bf(rd * v.x); o.y = (unsigned short)f2bf(rd * v.y);
        o.z = (unsigned short)f2bf(rd * v.z); o.w = (unsigned short)f2bf(rd * v.w);
        *(ushort4*)(x0s + i4) = o;
    }
}

// ---------------- pull SpMM layer 1: x1s = rdeg^2 * (sum of x0s rows) ----------------
// One 16-lane group per node (4 nodes/wave), lane owns 4 dims (uint2), 4 edges
// unrolled per iteration -> up to 16 independent gathers in flight per wave.
// No cross-lane reduction needed: each lane's dims are exclusive.
__global__ void spmm_pull_l1(const unsigned* __restrict__ rp,
                             const int* __restrict__ col,
                             const float* __restrict__ rdeg,
                             const uint2* __restrict__ x0s,
                             uint2* __restrict__ x1s, int N) {
    int node = blockIdx.x * (blockDim.x >> 4) + (threadIdx.x >> 4);
    int l = threadIdx.x & 15;
    if (node >= N) return;
    int e0 = (int)rp[node], e1 = (int)rp[node + 1];
    float a0 = 0.f, a1 = 0.f, a2 = 0.f, a3 = 0.f;
    int e = e0;
    for (; e + 4 <= e1; e += 4) {
        int c0 = col[e], c1 = col[e + 1], c2 = col[e + 2], c3 = col[e + 3];
        uint2 u0 = x0s[((size_t)c0 << 4) + l];
        uint2 u1 = x0s[((size_t)c1 << 4) + l];
        uint2 u2 = x0s[((size_t)c2 << 4) + l];
        uint2 u3 = x0s[((size_t)c3 << 4) + l];
        a0 += bflo(u0.x) + bflo(u1.x) + bflo(u2.x) + bflo(u3.x);
        a1 += bfhi(u0.x) + bfhi(u1.x) + bfhi(u2.x) + bfhi(u3.x);
        a2 += bflo(u0.y) + bflo(u1.y) + bflo(u2.y) + bflo(u3.y);
        a3 += bfhi(u0.y) + bfhi(u1.y) + bfhi(u2.y) + bfhi(u3.y);
    }
    for (; e < e1; ++e) {
        int c = col[e];
        uint2 u = x0s[((size_t)c << 4) + l];
        a0 += bflo(u.x); a1 += bfhi(u.x);
        a2 += bflo(u.y); a3 += bfhi(u.y);
    }
    float rd = rdeg[node];
    float rd2 = rd * rd;              // x1s = rdeg * x1 = rdeg^2 * sum
    uint2 o;
    o.x = (f2bf(rd2 * a1) << 16) | f2bf(rd2 * a0);
    o.y = (f2bf(rd2 * a3) << 16) | f2bf(rd2 * a2);
    x1s[((size_t)node << 4) + l] = o;
}

// ---------------- pull SpMM layer 2 fused with finalize ----------------
__global__ void spmm_l2_finalize(const unsigned* __restrict__ rp,
                                 const int* __restrict__ col,
                                 const float* __restrict__ rdeg,
                                 const float* __restrict__ rsq,
                                 const uint2* __restrict__ x0s,
                                 const uint2* __restrict__ x1s,
                                 float* __restrict__ out, int N) {
    int node = blockIdx.x * (blockDim.x >> 4) + (threadIdx.x >> 4);
    int l = threadIdx.x & 15;
    if (node >= N) return;
    int e0 = (int)rp[node], e1 = (int)rp[node + 1];
    float a0 = 0.f, a1 = 0.f, a2 = 0.f, a3 = 0.f;
    int e = e0;
    for (; e + 4 <= e1; e += 4) {
        int c0 = col[e], c1 = col[e + 1], c2 = col[e + 2], c3 = col[e + 3];
        uint2 u0 = x1s[((size_t)c0 << 4) + l];
        uint2 u1 = x1s[((size_t)c1 << 4) + l];
        uint2 u2 = x1s[((size_t)c2 << 4) + l];
        uint2 u3 = x1s[((size_t)c3 << 4) + l];
        a0 += bflo(u0.x) + bflo(u1.x) + bflo(u2.x) + bflo(u3.x);
        a1 += bfhi(u0.x) + bfhi(u1.x) + bfhi(u2.x) + bfhi(u3.x);
        a2 += bflo(u0.y) + bflo(u1.y) + bflo(u2.y) + bflo(u3.y);
        a3 += bfhi(u0.y) + bfhi(u1.y) + bfhi(u2.y) + bfhi(u3.y);
    }
    for (; e < e1; ++e) {
        int c = col[e];
        uint2 u = x1s[((size_t)c << 4) + l];
        a0 += bflo(u.x); a1 += bfhi(u.x);
        a2 += bflo(u.y); a3 += bfhi(u.y);
    }
    float rd = rdeg[node];
    a0 *= rd; a1 *= rd; a2 *= rd; a3 *= rd;     // x2 = rdeg * sum(x1s)
    // self terms: x0 = x0s*rsq, x1 = x1s*rsq
    float rq = rsq[node];
    uint2 u0 = x0s[((size_t)node << 4) + l];
    uint2 u1 = x1s[((size_t)node << 4) + l];
    float v0 = (rq * (bflo(u0.x) + bflo(u1.x)) + a0) * (1.0f / 3.0f);
    float v1 = (rq * (bfhi(u0.x) + bfhi(u1.x)) + a1) * (1.0f / 3.0f);
    float v2 = (rq * (bflo(u0.y) + bflo(u1.y)) + a2) * (1.0f / 3.0f);
    float v3 = (rq * (bfhi(u0.y) + bfhi(u1.y)) + a3) * (1.0f / 3.0f);
    // sum of squares across the 16-lane group
    float ss = v0 * v0 + v1 * v1 + v2 * v2 + v3 * v3;
    ss += __shfl_xor(ss, 1);
    ss += __shfl_xor(ss, 2);
    ss += __shfl_xor(ss, 4);
    ss += __shfl_xor(ss, 8);
    float theta = fmaxf(sqrtf(ss), 1e-7f);
    float ex  = __expf(theta);
    float exi = __builtin_amdgcn_rcpf(ex);
    float sh = 0.5f * (ex - exi);
    float ch = 0.5f * (ex + exi);
    float sc = sh * __builtin_amdgcn_rcpf(theta);
    float* o = out + (long)node * 129;
    float4 v4 = make_float4(v0, v1, v2, v3);
    *(float4*)(o + 4 * l) = v4;                 // dims 0..63
    if (l == 0) o[64] = ch;                     // time coordinate
    float4 l4 = make_float4(sc * v0, sc * v1, sc * v2, sc * v3);
    *(float4*)(o + 65 + 4 * l) = l4;            // lifted spatial part
}

extern "C" void kernel_launch(void* const* d_in, const int* in_sizes, int n_in,
                              void* d_out, int out_size, void* d_ws, size_t ws_size,
                              hipStream_t stream) {
    const float* ue = (const float*)d_in[0];
    const float* ie = (const float*)d_in[1];
    const int*   hl = (const int*)d_in[2];
    const int*   tl = (const int*)d_in[3];
    float* out = (float*)d_out;

    const int n_users = in_sizes[0] / DIM;
    const int n_items = in_sizes[1] / DIM;
    const int N = n_users + n_items;
    const int E = in_sizes[2];
    const int nb = (N + BSIZE - 1) >> BSHIFT;   // coarse buckets (<=MAXB)
    const long M = (long)N * DIM;

    // workspace layout (256B-aligned):
    // row_ptr[N+1] | rdeg[N] | rsq[N] | bcount | bbase | bcur
    //   | col[E] | tmp[E int2] | x0s[M u16] | x1s[M u16]
    auto align = [](size_t x) { return (x + 255) & ~(size_t)255; };
    char* p = (char*)d_ws;
    unsigned* row_ptr = (unsigned*)p;            p += align((size_t)(N + 1) * 4);
    float*    rdeg    = (float*)p;               p += align((size_t)N * 4);
    float*    rsq     = (float*)p;               p += align((size_t)N * 4);
    unsigned* bcount  = (unsigned*)p;            p += align((size_t)MAXB * 4);
    unsigned* bbase   = (unsigned*)p;            p += align((size_t)(MAXB + 1) * 4);
    unsigned* bcur    = (unsigned*)p;            p += align((size_t)MAXB * 4);
    int*      col     = (int*)p;                 p += align((size_t)E * 4);
    int2*     tmp     = (int2*)p;                p += align((size_t)E * 8);
    unsigned short* x0sh = (unsigned short*)p;   p += align((size_t)M * 2);
    unsigned short* x1sh = (unsigned short*)p;   // M u16
    const uint2* x0s = (const uint2*)x0sh;
    uint2* x1s = (uint2*)x1sh;

    // 1) zero bucket counts
    zero_u32<<<1, 256, 0, stream>>>(bcount, MAXB);

    // 2) coarse bucket histogram
    bucket_hist<<<512, 256, 0, stream>>>(hl, bcount, E, nb);

    // 3) scan bucket counts -> bbase/bcur; row_ptr[N]=E
    bucket_scan<<<1, MAXB, 0, stream>>>(bcount, bbase, bcur, row_ptr, nb, N, E);

    // 4) coarse partition of (h,t) by h>>BSHIFT into tmp
    {
        int blocks = (E + CHUNK - 1) / CHUNK;
        partition_edges<<<blocks, 256, 0, stream>>>(hl, tl, bcur, tmp, E, nb);
    }

    // 5) per-bucket CSR build (row_ptr, rdeg, rsq, col) — LDS atomics only
    build_csr_bucket<<<nb, 512, 0, stream>>>(tmp, bbase, row_ptr, rdeg, rsq, col, N);

    // 6) pre-scaled bf16 table x0s = rdeg * x0 (needs rdeg -> after CSR build)
    {
        long threads = (M + 3) / 4;
        int blocks = (int)((threads + 255) / 256);
        cvt_x0s<<<blocks, 256, 0, stream>>>(ue, ie, (long)n_users * DIM, rdeg, x0sh, M);
    }

    // 7) layer 1: x1s = rdeg^2 * sum(x0s)  (16-lane group per node)
    {
        int nodes_per_block = 256 / 16;
        int blocks = (N + nodes_per_block - 1) / nodes_per_block;
        spmm_pull_l1<<<blocks, 256, 0, stream>>>(row_ptr, col, rdeg, x0s, x1s, N);
    }

    // 8) layer 2 + finalize fused (16-lane group per node)
    {
        int nodes_per_block = 256 / 16;
        int blocks = (N + nodes_per_block - 1) / nodes_per_block;
        spmm_l2_finalize<<<blocks, 256, 0, stream>>>(row_ptr, col, rdeg, rsq,
                                                     x0s, x1s, out, N);
    }
}

// Round 11
// 338.243 us; speedup vs baseline: 2.1227x; 1.0343x over previous
//
#include <hip/hip_runtime.h>

#define DIM 64
#define CHUNK 16384       // edges per partition block
#define BSHIFT 11         // 2048 nodes per coarse bucket
#define BSIZE (1 << BSHIFT)
#define MAXB 128          // max coarse buckets (N<=262144)
#define TBITS 21          // bits for t in packed tmp (N < 2^21)
#define TMASK ((1u << TBITS) - 1u)

// ---- bf16 helpers (RNE) ----
__device__ __forceinline__ unsigned f2bf(float f) {
    unsigned u = __float_as_uint(f);
    return (u + 0x7FFFu + ((u >> 16) & 1u)) >> 16;
}
__device__ __forceinline__ float bflo(unsigned u) {   // low u16 -> f32
    return __uint_as_float(u << 16);
}
__device__ __forceinline__ float bfhi(unsigned u) {   // high u16 -> f32
    return __uint_as_float(u & 0xFFFF0000u);
}

// ---------------- zero u32 region ----------------
__global__ void zero_u32(unsigned* __restrict__ p, int n) {
    int i = blockIdx.x * blockDim.x + threadIdx.x;
    int stride = gridDim.x * blockDim.x;
    for (; i < n; i += stride) p[i] = 0u;
}

// ---------------- coarse bucket histogram (128 bins, LDS + global merge) ----------------
__global__ void bucket_hist(const int* __restrict__ h, unsigned* __restrict__ bcount,
                            int E, int nb) {
    __shared__ unsigned s[MAXB];
    for (int i = threadIdx.x; i < nb; i += blockDim.x) s[i] = 0u;
    __syncthreads();
    int i = blockIdx.x * blockDim.x + threadIdx.x;
    int stride = gridDim.x * blockDim.x;
    for (; i < E; i += stride) atomicAdd(&s[((unsigned)h[i]) >> BSHIFT], 1u);
    __syncthreads();
    for (int i = threadIdx.x; i < nb; i += blockDim.x)
        if (s[i]) atomicAdd(&bcount[i], s[i]);
}

// ---------------- scan bucket counts -> bbase/bcur (1 block of MAXB threads) ----------------
__global__ void bucket_scan(const unsigned* __restrict__ bcount,
                            unsigned* __restrict__ bbase, unsigned* __restrict__ bcur,
                            unsigned* __restrict__ row_ptr, int nb, int N, int E) {
    __shared__ unsigned s[MAXB];
    int tid = threadIdx.x;
    unsigned v = (tid < nb) ? bcount[tid] : 0u;
    s[tid] = v; __syncthreads();
    for (int off = 1; off < MAXB; off <<= 1) {
        unsigned t = (tid >= off) ? s[tid - off] : 0u;
        __syncthreads();
        s[tid] += t; __syncthreads();
    }
    if (tid < nb) {
        unsigned ex = s[tid] - v;   // exclusive
        bbase[tid] = ex;
        bcur[tid] = ex;
    }
    if (tid == 0) {
        bbase[nb] = (unsigned)E;
        row_ptr[N] = (unsigned)E;
    }
}

// ---------------- coarse partition: packed (hloc,t) -> bucket-contiguous tmp ----------------
__global__ void partition_edges(const int* __restrict__ h, const int* __restrict__ t,
                                unsigned* __restrict__ bcur, unsigned* __restrict__ tmp,
                                int E, int nb) {
    __shared__ unsigned cnt[MAXB];
    int tid = threadIdx.x;
    long start = (long)blockIdx.x * CHUNK;
    long end = start + CHUNK; if (end > E) end = E;
    for (int i = tid; i < nb; i += blockDim.x) cnt[i] = 0u;
    __syncthreads();
    for (long i = start + tid; i < end; i += blockDim.x)
        atomicAdd(&cnt[((unsigned)h[i]) >> BSHIFT], 1u);
    __syncthreads();
    for (int i = tid; i < nb; i += blockDim.x) {
        unsigned c = cnt[i];
        cnt[i] = c ? atomicAdd(&bcur[i], c) : 0u;   // reserve chunk; cnt becomes cursor
    }
    __syncthreads();
    for (long i = start + tid; i < end; i += blockDim.x) {
        unsigned hn = (unsigned)h[i], tn = (unsigned)t[i];
        unsigned pos = atomicAdd(&cnt[hn >> BSHIFT], 1u);
        tmp[pos] = ((hn & (BSIZE - 1)) << TBITS) | tn;   // 11-bit hloc | 21-bit t
    }
}

// ---------------- per-bucket CSR build: LDS histogram + scan + LDS-atomic place ----------------
__global__ void build_csr_bucket(const unsigned* __restrict__ tmp,
                                 const unsigned* __restrict__ bbase,
                                 unsigned* __restrict__ row_ptr,
                                 float* __restrict__ rdeg,
                                 float* __restrict__ rsq,
                                 int* __restrict__ col, int N) {
    __shared__ unsigned cnt[BSIZE];
    __shared__ unsigned cur[BSIZE];
    __shared__ unsigned ts[512];
    int b = blockIdx.x;
    int tid = threadIdx.x;
    unsigned e0 = bbase[b], e1 = bbase[b + 1];
    int nlo = b << BSHIFT;
    int nloc = N - nlo; if (nloc > BSIZE) nloc = BSIZE;
    for (int i = tid; i < nloc; i += 512) cnt[i] = 0u;
    __syncthreads();
    for (unsigned i = e0 + tid; i < e1; i += 512)
        atomicAdd(&cnt[tmp[i] >> TBITS], 1u);
    __syncthreads();
    // exclusive scan over cnt[0..nloc): 512 threads x 4 elems
    int base = tid * 4;
    unsigned mysum = 0;
    #pragma unroll
    for (int j = 0; j < 4; ++j) { int i = base + j; if (i < nloc) mysum += cnt[i]; }
    ts[tid] = mysum; __syncthreads();
    for (int off = 1; off < 512; off <<= 1) {
        unsigned t = (tid >= off) ? ts[tid - off] : 0u;
        __syncthreads();
        ts[tid] += t; __syncthreads();
    }
    unsigned off0 = ts[tid] - mysum;
    #pragma unroll
    for (int j = 0; j < 4; ++j) {
        int i = base + j;
        if (i < nloc) {
            unsigned c = cnt[i];
            float d = fmaxf((float)c, 1.0f);
            cur[i] = off0;
            row_ptr[nlo + i] = e0 + off0;
            rdeg[nlo + i] = rsqrtf(d);
            rsq[nlo + i]  = sqrtf(d);
            off0 += c;
        }
    }
    __syncthreads();
    for (unsigned i = e0 + tid; i < e1; i += 512) {
        unsigned pk = tmp[i];
        unsigned pos = e0 + atomicAdd(&cur[pk >> TBITS], 1u);
        col[pos] = (int)(pk & TMASK);
    }
}

// ---------------- convert concat(ue,ie) f32 -> PRE-SCALED bf16 table ----------------
__global__ void cvt_x0s(const float* __restrict__ ue, const float* __restrict__ ie,
                        long nu_elems, const float* __restrict__ rdeg,
                        unsigned short* __restrict__ x0s, long M) {
    long i4 = ((long)blockIdx.x * blockDim.x + threadIdx.x) * 4;
    long stride = (long)gridDim.x * blockDim.x * 4;
    for (; i4 < M; i4 += stride) {
        const float* src = (i4 < nu_elems) ? ue + i4 : ie + (i4 - nu_elems);
        float rd = rdeg[i4 >> 6];
        float4 v = *(const float4*)src;
        ushort4 o;
        o.x = (unsigned short)f2bf(rd * v.x); o.y = (unsigned short)f2bf(rd * v.y);
        o.z = (unsigned short)f2bf(rd * v.z); o.w = (unsigned short)f2bf(rd * v.w);
        *(ushort4*)(x0s + i4) = o;
    }
}

// ---------------- pull SpMM layer 1: x1s = rdeg^2 * (sum of x0s rows) ----------------
// One 8-lane group per node (8 nodes/wave), lane owns 8 dims (uint4 = 16B),
// 4 edges unrolled -> up to 32 independent gathers in flight per wave.
__global__ void spmm_pull_l1(const unsigned* __restrict__ rp,
                             const int* __restrict__ col,
                             const float* __restrict__ rdeg,
                             const uint4* __restrict__ x0s,
                             uint4* __restrict__ x1s, int N) {
    int node = blockIdx.x * (blockDim.x >> 3) + (threadIdx.x >> 3);
    int l = threadIdx.x & 7;
    if (node >= N) return;
    int e0 = (int)rp[node], e1 = (int)rp[node + 1];
    float a0 = 0.f, a1 = 0.f, a2 = 0.f, a3 = 0.f;
    float a4 = 0.f, a5 = 0.f, a6 = 0.f, a7 = 0.f;
    int e = e0;
    for (; e + 4 <= e1; e += 4) {
        int c0 = col[e], c1 = col[e + 1], c2 = col[e + 2], c3 = col[e + 3];
        uint4 u0 = x0s[((size_t)c0 << 3) + l];
        uint4 u1 = x0s[((size_t)c1 << 3) + l];
        uint4 u2 = x0s[((size_t)c2 << 3) + l];
        uint4 u3 = x0s[((size_t)c3 << 3) + l];
        a0 += bflo(u0.x) + bflo(u1.x) + bflo(u2.x) + bflo(u3.x);
        a1 += bfhi(u0.x) + bfhi(u1.x) + bfhi(u2.x) + bfhi(u3.x);
        a2 += bflo(u0.y) + bflo(u1.y) + bflo(u2.y) + bflo(u3.y);
        a3 += bfhi(u0.y) + bfhi(u1.y) + bfhi(u2.y) + bfhi(u3.y);
        a4 += bflo(u0.z) + bflo(u1.z) + bflo(u2.z) + bflo(u3.z);
        a5 += bfhi(u0.z) + bfhi(u1.z) + bfhi(u2.z) + bfhi(u3.z);
        a6 += bflo(u0.w) + bflo(u1.w) + bflo(u2.w) + bflo(u3.w);
        a7 += bfhi(u0.w) + bfhi(u1.w) + bfhi(u2.w) + bfhi(u3.w);
    }
    for (; e < e1; ++e) {
        int c = col[e];
        uint4 u = x0s[((size_t)c << 3) + l];
        a0 += bflo(u.x); a1 += bfhi(u.x);
        a2 += bflo(u.y); a3 += bfhi(u.y);
        a4 += bflo(u.z); a5 += bfhi(u.z);
        a6 += bflo(u.w); a7 += bfhi(u.w);
    }
    float rd = rdeg[node];
    float rd2 = rd * rd;              // x1s = rdeg * x1 = rdeg^2 * sum
    uint4 o;
    o.x = (f2bf(rd2 * a1) << 16) | f2bf(rd2 * a0);
    o.y = (f2bf(rd2 * a3) << 16) | f2bf(rd2 * a2);
    o.z = (f2bf(rd2 * a5) << 16) | f2bf(rd2 * a4);
    o.w = (f2bf(rd2 * a7) << 16) | f2bf(rd2 * a6);
    x1s[((size_t)node << 3) + l] = o;
}

// ---------------- pull SpMM layer 2 fused with finalize ----------------
__global__ void spmm_l2_finalize(const unsigned* __restrict__ rp,
                                 const int* __restrict__ col,
                                 const float* __restrict__ rdeg,
                                 const float* __restrict__ rsq,
                                 const uint4* __restrict__ x0s,
                                 const uint4* __restrict__ x1s,
                                 float* __restrict__ out, int N) {
    int node = blockIdx.x * (blockDim.x >> 3) + (threadIdx.x >> 3);
    int l = threadIdx.x & 7;
    if (node >= N) return;
    int e0 = (int)rp[node], e1 = (int)rp[node + 1];
    float a0 = 0.f, a1 = 0.f, a2 = 0.f, a3 = 0.f;
    float a4 = 0.f, a5 = 0.f, a6 = 0.f, a7 = 0.f;
    int e = e0;
    for (; e + 4 <= e1; e += 4) {
        int c0 = col[e], c1 = col[e + 1], c2 = col[e + 2], c3 = col[e + 3];
        uint4 u0 = x1s[((size_t)c0 << 3) + l];
        uint4 u1 = x1s[((size_t)c1 << 3) + l];
        uint4 u2 = x1s[((size_t)c2 << 3) + l];
        uint4 u3 = x1s[((size_t)c3 << 3) + l];
        a0 += bflo(u0.x) + bflo(u1.x) + bflo(u2.x) + bflo(u3.x);
        a1 += bfhi(u0.x) + bfhi(u1.x) + bfhi(u2.x) + bfhi(u3.x);
        a2 += bflo(u0.y) + bflo(u1.y) + bflo(u2.y) + bflo(u3.y);
        a3 += bfhi(u0.y) + bfhi(u1.y) + bfhi(u2.y) + bfhi(u3.y);
        a4 += bflo(u0.z) + bflo(u1.z) + bflo(u2.z) + bflo(u3.z);
        a5 += bfhi(u0.z) + bfhi(u1.z) + bfhi(u2.z) + bfhi(u3.z);
        a6 += bflo(u0.w) + bflo(u1.w) + bflo(u2.w) + bflo(u3.w);
        a7 += bfhi(u0.w) + bfhi(u1.w) + bfhi(u2.w) + bfhi(u3.w);
    }
    for (; e < e1; ++e) {
        int c = col[e];
        uint4 u = x1s[((size_t)c << 3) + l];
        a0 += bflo(u.x); a1 += bfhi(u.x);
        a2 += bflo(u.y); a3 += bfhi(u.y);
        a4 += bflo(u.z); a5 += bfhi(u.z);
        a6 += bflo(u.w); a7 += bfhi(u.w);
    }
    float rd = rdeg[node];
    a0 *= rd; a1 *= rd; a2 *= rd; a3 *= rd;
    a4 *= rd; a5 *= rd; a6 *= rd; a7 *= rd;     // x2 = rdeg * sum(x1s)
    // self terms: x0 = x0s*rsq, x1 = x1s*rsq
    float rq = rsq[node];
    uint4 u0 = x0s[((size_t)node << 3) + l];
    uint4 u1 = x1s[((size_t)node << 3) + l];
    float v0 = (rq * (bflo(u0.x) + bflo(u1.x)) + a0) * (1.0f / 3.0f);
    float v1 = (rq * (bfhi(u0.x) + bfhi(u1.x)) + a1) * (1.0f / 3.0f);
    float v2 = (rq * (bflo(u0.y) + bflo(u1.y)) + a2) * (1.0f / 3.0f);
    float v3 = (rq * (bfhi(u0.y) + bfhi(u1.y)) + a3) * (1.0f / 3.0f);
    float v4 = (rq * (bflo(u0.z) + bflo(u1.z)) + a4) * (1.0f / 3.0f);
    float v5 = (rq * (bfhi(u0.z) + bfhi(u1.z)) + a5) * (1.0f / 3.0f);
    float v6 = (rq * (bflo(u0.w) + bflo(u1.w)) + a6) * (1.0f / 3.0f);
    float v7 = (rq * (bfhi(u0.w) + bfhi(u1.w)) + a7) * (1.0f / 3.0f);
    // sum of squares across the 8-lane group
    float ss = v0*v0 + v1*v1 + v2*v2 + v3*v3 + v4*v4 + v5*v5 + v6*v6 + v7*v7;
    ss += __shfl_xor(ss, 1);
    ss += __shfl_xor(ss, 2);
    ss += __shfl_xor(ss, 4);
    float theta = fmaxf(sqrtf(ss), 1e-7f);
    float ex  = __expf(theta);
    float exi = __builtin_amdgcn_rcpf(ex);
    float sh = 0.5f * (ex - exi);
    float ch = 0.5f * (ex + exi);
    float sc = sh * __builtin_amdgcn_rcpf(theta);
    float* o = out + (long)node * 129;
    *(float4*)(o + 8 * l)     = make_float4(v0, v1, v2, v3);   // dims 0..63
    *(float4*)(o + 8 * l + 4) = make_float4(v4, v5, v6, v7);
    if (l == 0) o[64] = ch;                                    // time coordinate
    *(float4*)(o + 65 + 8 * l)     = make_float4(sc*v0, sc*v1, sc*v2, sc*v3);
    *(float4*)(o + 65 + 8 * l + 4) = make_float4(sc*v4, sc*v5, sc*v6, sc*v7);
}

extern "C" void kernel_launch(void* const* d_in, const int* in_sizes, int n_in,
                              void* d_out, int out_size, void* d_ws, size_t ws_size,
                              hipStream_t stream) {
    const float* ue = (const float*)d_in[0];
    const float* ie = (const float*)d_in[1];
    const int*   hl = (const int*)d_in[2];
    const int*   tl = (const int*)d_in[3];
    float* out = (float*)d_out;

    const int n_users = in_sizes[0] / DIM;
    const int n_items = in_sizes[1] / DIM;
    const int N = n_users + n_items;
    const int E = in_sizes[2];
    const int nb = (N + BSIZE - 1) >> BSHIFT;   // coarse buckets (<=MAXB)
    const long M = (long)N * DIM;

    // workspace layout (256B-aligned):
    // row_ptr[N+1] | rdeg[N] | rsq[N] | bcount | bbase | bcur
    //   | col[E] | tmp[E u32] | x0s[M u16] | x1s[M u16]
    auto align = [](size_t x) { return (x + 255) & ~(size_t)255; };
    char* p = (char*)d_ws;
    unsigned* row_ptr = (unsigned*)p;            p += align((size_t)(N + 1) * 4);
    float*    rdeg    = (float*)p;               p += align((size_t)N * 4);
    float*    rsq     = (float*)p;               p += align((size_t)N * 4);
    unsigned* bcount  = (unsigned*)p;            p += align((size_t)MAXB * 4);
    unsigned* bbase   = (unsigned*)p;            p += align((size_t)(MAXB + 1) * 4);
    unsigned* bcur    = (unsigned*)p;            p += align((size_t)MAXB * 4);
    int*      col     = (int*)p;                 p += align((size_t)E * 4);
    unsigned* tmp     = (unsigned*)p;            p += align((size_t)E * 4);
    unsigned short* x0sh = (unsigned short*)p;   p += align((size_t)M * 2);
    unsigned short* x1sh = (unsigned short*)p;   // M u16
    const uint4* x0s = (const uint4*)x0sh;
    uint4* x1s = (uint4*)x1sh;

    // 1) zero bucket counts
    zero_u32<<<1, 256, 0, stream>>>(bcount, MAXB);

    // 2) coarse bucket histogram
    bucket_hist<<<512, 256, 0, stream>>>(hl, bcount, E, nb);

    // 3) scan bucket counts -> bbase/bcur; row_ptr[N]=E
    bucket_scan<<<1, MAXB, 0, stream>>>(bcount, bbase, bcur, row_ptr, nb, N, E);

    // 4) coarse partition of packed (hloc,t) by h>>BSHIFT into tmp
    {
        int blocks = (E + CHUNK - 1) / CHUNK;
        partition_edges<<<blocks, 256, 0, stream>>>(hl, tl, bcur, tmp, E, nb);
    }

    // 5) per-bucket CSR build (row_ptr, rdeg, rsq, col) — LDS atomics only
    build_csr_bucket<<<nb, 512, 0, stream>>>(tmp, bbase, row_ptr, rdeg, rsq, col, N);

    // 6) pre-scaled bf16 table x0s = rdeg * x0 (needs rdeg -> after CSR build)
    {
        long threads = (M + 3) / 4;
        int blocks = (int)((threads + 255) / 256);
        cvt_x0s<<<blocks, 256, 0, stream>>>(ue, ie, (long)n_users * DIM, rdeg, x0sh, M);
    }

    // 7) layer 1: x1s = rdeg^2 * sum(x0s)  (8-lane group per node)
    {
        int nodes_per_block = 256 / 8;
        int blocks = (N + nodes_per_block - 1) / nodes_per_block;
        spmm_pull_l1<<<blocks, 256, 0, stream>>>(row_ptr, col, rdeg, x0s, x1s, N);
    }

    // 8) layer 2 + finalize fused (8-lane group per node)
    {
        int nodes_per_block = 256 / 8;
        int blocks = (N + nodes_per_block - 1) / nodes_per_block;
        spmm_l2_finalize<<<blocks, 256, 0, stream>>>(row_ptr, col, rdeg, rsq,
                                                     x0s, x1s, out, N);
    }
}

// Round 12
// 333.222 us; speedup vs baseline: 2.1546x; 1.0151x over previous
//
#include <hip/hip_runtime.h>

#define DIM 64
#define CHUNK 16384       // edges per partition block
#define BSHIFT 10         // 1024 nodes per coarse bucket
#define BSIZE (1 << BSHIFT)
#define MAXB 256          // max coarse buckets (N<=262144)
#define TBITS 21          // bits for t in packed tmp (N < 2^21)
#define TMASK ((1u << TBITS) - 1u)

// ---- bf16 helpers (RNE) ----
__device__ __forceinline__ unsigned f2bf(float f) {
    unsigned u = __float_as_uint(f);
    return (u + 0x7FFFu + ((u >> 16) & 1u)) >> 16;
}
__device__ __forceinline__ float bflo(unsigned u) {   // low u16 -> f32
    return __uint_as_float(u << 16);
}
__device__ __forceinline__ float bfhi(unsigned u) {   // high u16 -> f32
    return __uint_as_float(u & 0xFFFF0000u);
}

// ---------------- zero u32 region ----------------
__global__ void zero_u32(unsigned* __restrict__ p, int n) {
    int i = blockIdx.x * blockDim.x + threadIdx.x;
    int stride = gridDim.x * blockDim.x;
    for (; i < n; i += stride) p[i] = 0u;
}

// ---------------- coarse bucket histogram (256 bins, LDS + global merge) ----------------
__global__ void bucket_hist(const int* __restrict__ h, unsigned* __restrict__ bcount,
                            int E, int nb) {
    __shared__ unsigned s[MAXB];
    for (int i = threadIdx.x; i < nb; i += blockDim.x) s[i] = 0u;
    __syncthreads();
    int i = blockIdx.x * blockDim.x + threadIdx.x;
    int stride = gridDim.x * blockDim.x;
    for (; i < E; i += stride) atomicAdd(&s[((unsigned)h[i]) >> BSHIFT], 1u);
    __syncthreads();
    for (int i = threadIdx.x; i < nb; i += blockDim.x)
        if (s[i]) atomicAdd(&bcount[i], s[i]);
}

// ---------------- scan bucket counts -> bbase/bcur (1 block of MAXB threads) ----------------
__global__ void bucket_scan(const unsigned* __restrict__ bcount,
                            unsigned* __restrict__ bbase, unsigned* __restrict__ bcur,
                            unsigned* __restrict__ row_ptr, int nb, int N, int E) {
    __shared__ unsigned s[MAXB];
    int tid = threadIdx.x;
    unsigned v = (tid < nb) ? bcount[tid] : 0u;
    s[tid] = v; __syncthreads();
    for (int off = 1; off < MAXB; off <<= 1) {
        unsigned t = (tid >= off) ? s[tid - off] : 0u;
        __syncthreads();
        s[tid] += t; __syncthreads();
    }
    if (tid < nb) {
        unsigned ex = s[tid] - v;   // exclusive
        bbase[tid] = ex;
        bcur[tid] = ex;
    }
    if (tid == 0) {
        bbase[nb] = (unsigned)E;
        row_ptr[N] = (unsigned)E;
    }
}

// ---------------- coarse partition: packed (hloc,t) -> bucket-contiguous tmp ----------------
__global__ void partition_edges(const int* __restrict__ h, const int* __restrict__ t,
                                unsigned* __restrict__ bcur, unsigned* __restrict__ tmp,
                                int E, int nb) {
    __shared__ unsigned cnt[MAXB];
    int tid = threadIdx.x;
    long start = (long)blockIdx.x * CHUNK;
    long end = start + CHUNK; if (end > E) end = E;
    for (int i = tid; i < nb; i += blockDim.x) cnt[i] = 0u;
    __syncthreads();
    for (long i = start + tid; i < end; i += blockDim.x)
        atomicAdd(&cnt[((unsigned)h[i]) >> BSHIFT], 1u);
    __syncthreads();
    for (int i = tid; i < nb; i += blockDim.x) {
        unsigned c = cnt[i];
        cnt[i] = c ? atomicAdd(&bcur[i], c) : 0u;   // reserve chunk; cnt becomes cursor
    }
    __syncthreads();
    for (long i = start + tid; i < end; i += blockDim.x) {
        unsigned hn = (unsigned)h[i], tn = (unsigned)t[i];
        unsigned pos = atomicAdd(&cnt[hn >> BSHIFT], 1u);
        tmp[pos] = ((hn & (BSIZE - 1)) << TBITS) | tn;   // 10-bit hloc | 21-bit t
    }
}

// ---------------- per-bucket CSR build + fused x0s convert ----------------
// One block per bucket (1024 nodes). LDS histogram -> scan -> row_ptr/rdeg/rsq,
// LDS-atomic col placement, then converts its own 1024 rows to pre-scaled bf16.
__global__ void build_csr_bucket(const unsigned* __restrict__ tmp,
                                 const unsigned* __restrict__ bbase,
                                 unsigned* __restrict__ row_ptr,
                                 float* __restrict__ rdeg,
                                 float* __restrict__ rsq,
                                 int* __restrict__ col,
                                 const float* __restrict__ ue,
                                 const float* __restrict__ ie,
                                 int n_users,
                                 unsigned short* __restrict__ x0s, int N) {
    __shared__ unsigned cnt[BSIZE];
    __shared__ unsigned cur[BSIZE];
    __shared__ unsigned ts[512];
    int b = blockIdx.x;
    int tid = threadIdx.x;
    unsigned e0 = bbase[b], e1 = bbase[b + 1];
    int nlo = b << BSHIFT;
    int nloc = N - nlo; if (nloc > BSIZE) nloc = BSIZE;
    for (int i = tid; i < nloc; i += 512) cnt[i] = 0u;
    __syncthreads();
    for (unsigned i = e0 + tid; i < e1; i += 512)
        atomicAdd(&cnt[tmp[i] >> TBITS], 1u);
    __syncthreads();
    // exclusive scan over cnt[0..nloc): 512 threads x 2 elems
    int base = tid * 2;
    unsigned mysum = 0;
    #pragma unroll
    for (int j = 0; j < 2; ++j) { int i = base + j; if (i < nloc) mysum += cnt[i]; }
    ts[tid] = mysum; __syncthreads();
    for (int off = 1; off < 512; off <<= 1) {
        unsigned t = (tid >= off) ? ts[tid - off] : 0u;
        __syncthreads();
        ts[tid] += t; __syncthreads();
    }
    unsigned off0 = ts[tid] - mysum;
    #pragma unroll
    for (int j = 0; j < 2; ++j) {
        int i = base + j;
        if (i < nloc) {
            unsigned c = cnt[i];
            float d = fmaxf((float)c, 1.0f);
            cur[i] = off0;
            row_ptr[nlo + i] = e0 + off0;
            rdeg[nlo + i] = rsqrtf(d);
            rsq[nlo + i]  = sqrtf(d);
            off0 += c;
        }
    }
    __syncthreads();
    // place edges (LDS atomics only; col window ~64KB, L2-local)
    for (unsigned i = e0 + tid; i < e1; i += 512) {
        unsigned pk = tmp[i];
        unsigned pos = e0 + atomicAdd(&cur[pk >> TBITS], 1u);
        col[pos] = (int)(pk & TMASK);
    }
    // fused convert: this bucket's rows -> pre-scaled bf16 x0s (cnt is intact)
    long nu_elems = (long)n_users * DIM;
    int total = nloc * 16;   // 16 float4-chunks per 64-dim row
    for (int idx = tid; idx < total; idx += 512) {
        int i = idx >> 4, j = idx & 15;
        long n = (long)(nlo + i);
        long elem = n * DIM + j * 4;
        const float* src = (elem < nu_elems) ? ue + elem : ie + (elem - nu_elems);
        float rd = rsqrtf(fmaxf((float)cnt[i], 1.0f));
        float4 v = *(const float4*)src;
        ushort4 o;
        o.x = (unsigned short)f2bf(rd * v.x); o.y = (unsigned short)f2bf(rd * v.y);
        o.z = (unsigned short)f2bf(rd * v.z); o.w = (unsigned short)f2bf(rd * v.w);
        *(ushort4*)(x0s + elem) = o;
    }
}

// ---------------- pull SpMM layer 1: x1s = rdeg^2 * (sum of x0s rows) ----------------
// One 8-lane group per node (8 nodes/wave), lane owns 8 dims (uint4 = 16B),
// 4 edges unrolled -> up to 32 independent gathers in flight per wave.
__global__ void spmm_pull_l1(const unsigned* __restrict__ rp,
                             const int* __restrict__ col,
                             const float* __restrict__ rdeg,
                             const uint4* __restrict__ x0s,
                             uint4* __restrict__ x1s, int N) {
    int node = blockIdx.x * (blockDim.x >> 3) + (threadIdx.x >> 3);
    int l = threadIdx.x & 7;
    if (node >= N) return;
    int e0 = (int)rp[node], e1 = (int)rp[node + 1];
    float a0 = 0.f, a1 = 0.f, a2 = 0.f, a3 = 0.f;
    float a4 = 0.f, a5 = 0.f, a6 = 0.f, a7 = 0.f;
    int e = e0;
    for (; e + 4 <= e1; e += 4) {
        int c0 = col[e], c1 = col[e + 1], c2 = col[e + 2], c3 = col[e + 3];
        uint4 u0 = x0s[((size_t)c0 << 3) + l];
        uint4 u1 = x0s[((size_t)c1 << 3) + l];
        uint4 u2 = x0s[((size_t)c2 << 3) + l];
        uint4 u3 = x0s[((size_t)c3 << 3) + l];
        a0 += bflo(u0.x) + bflo(u1.x) + bflo(u2.x) + bflo(u3.x);
        a1 += bfhi(u0.x) + bfhi(u1.x) + bfhi(u2.x) + bfhi(u3.x);
        a2 += bflo(u0.y) + bflo(u1.y) + bflo(u2.y) + bflo(u3.y);
        a3 += bfhi(u0.y) + bfhi(u1.y) + bfhi(u2.y) + bfhi(u3.y);
        a4 += bflo(u0.z) + bflo(u1.z) + bflo(u2.z) + bflo(u3.z);
        a5 += bfhi(u0.z) + bfhi(u1.z) + bfhi(u2.z) + bfhi(u3.z);
        a6 += bflo(u0.w) + bflo(u1.w) + bflo(u2.w) + bflo(u3.w);
        a7 += bfhi(u0.w) + bfhi(u1.w) + bfhi(u2.w) + bfhi(u3.w);
    }
    for (; e < e1; ++e) {
        int c = col[e];
        uint4 u = x0s[((size_t)c << 3) + l];
        a0 += bflo(u.x); a1 += bfhi(u.x);
        a2 += bflo(u.y); a3 += bfhi(u.y);
        a4 += bflo(u.z); a5 += bfhi(u.z);
        a6 += bflo(u.w); a7 += bfhi(u.w);
    }
    float rd = rdeg[node];
    float rd2 = rd * rd;              // x1s = rdeg * x1 = rdeg^2 * sum
    uint4 o;
    o.x = (f2bf(rd2 * a1) << 16) | f2bf(rd2 * a0);
    o.y = (f2bf(rd2 * a3) << 16) | f2bf(rd2 * a2);
    o.z = (f2bf(rd2 * a5) << 16) | f2bf(rd2 * a4);
    o.w = (f2bf(rd2 * a7) << 16) | f2bf(rd2 * a6);
    x1s[((size_t)node << 3) + l] = o;
}

// ---------------- pull SpMM layer 2 fused with finalize ----------------
__global__ void spmm_l2_finalize(const unsigned* __restrict__ rp,
                                 const int* __restrict__ col,
                                 const float* __restrict__ rdeg,
                                 const float* __restrict__ rsq,
                                 const uint4* __restrict__ x0s,
                                 const uint4* __restrict__ x1s,
                                 float* __restrict__ out, int N) {
    int node = blockIdx.x * (blockDim.x >> 3) + (threadIdx.x >> 3);
    int l = threadIdx.x & 7;
    if (node >= N) return;
    int e0 = (int)rp[node], e1 = (int)rp[node + 1];
    float a0 = 0.f, a1 = 0.f, a2 = 0.f, a3 = 0.f;
    float a4 = 0.f, a5 = 0.f, a6 = 0.f, a7 = 0.f;
    int e = e0;
    for (; e + 4 <= e1; e += 4) {
        int c0 = col[e], c1 = col[e + 1], c2 = col[e + 2], c3 = col[e + 3];
        uint4 u0 = x1s[((size_t)c0 << 3) + l];
        uint4 u1 = x1s[((size_t)c1 << 3) + l];
        uint4 u2 = x1s[((size_t)c2 << 3) + l];
        uint4 u3 = x1s[((size_t)c3 << 3) + l];
        a0 += bflo(u0.x) + bflo(u1.x) + bflo(u2.x) + bflo(u3.x);
        a1 += bfhi(u0.x) + bfhi(u1.x) + bfhi(u2.x) + bfhi(u3.x);
        a2 += bflo(u0.y) + bflo(u1.y) + bflo(u2.y) + bflo(u3.y);
        a3 += bfhi(u0.y) + bfhi(u1.y) + bfhi(u2.y) + bfhi(u3.y);
        a4 += bflo(u0.z) + bflo(u1.z) + bflo(u2.z) + bflo(u3.z);
        a5 += bfhi(u0.z) + bfhi(u1.z) + bfhi(u2.z) + bfhi(u3.z);
        a6 += bflo(u0.w) + bflo(u1.w) + bflo(u2.w) + bflo(u3.w);
        a7 += bfhi(u0.w) + bfhi(u1.w) + bfhi(u2.w) + bfhi(u3.w);
    }
    for (; e < e1; ++e) {
        int c = col[e];
        uint4 u = x1s[((size_t)c << 3) + l];
        a0 += bflo(u.x); a1 += bfhi(u.x);
        a2 += bflo(u.y); a3 += bfhi(u.y);
        a4 += bflo(u.z); a5 += bfhi(u.z);
        a6 += bflo(u.w); a7 += bfhi(u.w);
    }
    float rd = rdeg[node];
    a0 *= rd; a1 *= rd; a2 *= rd; a3 *= rd;
    a4 *= rd; a5 *= rd; a6 *= rd; a7 *= rd;     // x2 = rdeg * sum(x1s)
    // self terms: x0 = x0s*rsq, x1 = x1s*rsq
    float rq = rsq[node];
    uint4 u0 = x0s[((size_t)node << 3) + l];
    uint4 u1 = x1s[((size_t)node << 3) + l];
    float v0 = (rq * (bflo(u0.x) + bflo(u1.x)) + a0) * (1.0f / 3.0f);
    float v1 = (rq * (bfhi(u0.x) + bfhi(u1.x)) + a1) * (1.0f / 3.0f);
    float v2 = (rq * (bflo(u0.y) + bflo(u1.y)) + a2) * (1.0f / 3.0f);
    float v3 = (rq * (bfhi(u0.y) + bfhi(u1.y)) + a3) * (1.0f / 3.0f);
    float v4 = (rq * (bflo(u0.z) + bflo(u1.z)) + a4) * (1.0f / 3.0f);
    float v5 = (rq * (bfhi(u0.z) + bfhi(u1.z)) + a5) * (1.0f / 3.0f);
    float v6 = (rq * (bflo(u0.w) + bflo(u1.w)) + a6) * (1.0f / 3.0f);
    float v7 = (rq * (bfhi(u0.w) + bfhi(u1.w)) + a7) * (1.0f / 3.0f);
    // sum of squares across the 8-lane group
    float ss = v0*v0 + v1*v1 + v2*v2 + v3*v3 + v4*v4 + v5*v5 + v6*v6 + v7*v7;
    ss += __shfl_xor(ss, 1);
    ss += __shfl_xor(ss, 2);
    ss += __shfl_xor(ss, 4);
    float theta = fmaxf(sqrtf(ss), 1e-7f);
    float ex  = __expf(theta);
    float exi = __builtin_amdgcn_rcpf(ex);
    float sh = 0.5f * (ex - exi);
    float ch = 0.5f * (ex + exi);
    float sc = sh * __builtin_amdgcn_rcpf(theta);
    float* o = out + (long)node * 129;
    *(float4*)(o + 8 * l)     = make_float4(v0, v1, v2, v3);   // dims 0..63
    *(float4*)(o + 8 * l + 4) = make_float4(v4, v5, v6, v7);
    if (l == 0) o[64] = ch;                                    // time coordinate
    *(float4*)(o + 65 + 8 * l)     = make_float4(sc*v0, sc*v1, sc*v2, sc*v3);
    *(float4*)(o + 65 + 8 * l + 4) = make_float4(sc*v4, sc*v5, sc*v6, sc*v7);
}

extern "C" void kernel_launch(void* const* d_in, const int* in_sizes, int n_in,
                              void* d_out, int out_size, void* d_ws, size_t ws_size,
                              hipStream_t stream) {
    const float* ue = (const float*)d_in[0];
    const float* ie = (const float*)d_in[1];
    const int*   hl = (const int*)d_in[2];
    const int*   tl = (const int*)d_in[3];
    float* out = (float*)d_out;

    const int n_users = in_sizes[0] / DIM;
    const int n_items = in_sizes[1] / DIM;
    const int N = n_users + n_items;
    const int E = in_sizes[2];
    const int nb = (N + BSIZE - 1) >> BSHIFT;   // coarse buckets (<=MAXB)
    const long M = (long)N * DIM;

    // workspace layout (256B-aligned):
    // row_ptr[N+1] | rdeg[N] | rsq[N] | bcount | bbase | bcur
    //   | col[E] | tmp[E u32] | x0s[M u16] | x1s[M u16]
    auto align = [](size_t x) { return (x + 255) & ~(size_t)255; };
    char* p = (char*)d_ws;
    unsigned* row_ptr = (unsigned*)p;            p += align((size_t)(N + 1) * 4);
    float*    rdeg    = (float*)p;               p += align((size_t)N * 4);
    float*    rsq     = (float*)p;               p += align((size_t)N * 4);
    unsigned* bcount  = (unsigned*)p;            p += align((size_t)MAXB * 4);
    unsigned* bbase   = (unsigned*)p;            p += align((size_t)(MAXB + 1) * 4);
    unsigned* bcur    = (unsigned*)p;            p += align((size_t)MAXB * 4);
    int*      col     = (int*)p;                 p += align((size_t)E * 4);
    unsigned* tmp     = (unsigned*)p;            p += align((size_t)E * 4);
    unsigned short* x0sh = (unsigned short*)p;   p += align((size_t)M * 2);
    unsigned short* x1sh = (unsigned short*)p;   // M u16
    const uint4* x0s = (const uint4*)x0sh;
    uint4* x1s = (uint4*)x1sh;

    // 1) zero bucket counts
    zero_u32<<<1, 256, 0, stream>>>(bcount, MAXB);

    // 2) coarse bucket histogram
    bucket_hist<<<512, 256, 0, stream>>>(hl, bcount, E, nb);

    // 3) scan bucket counts -> bbase/bcur; row_ptr[N]=E
    bucket_scan<<<1, MAXB, 0, stream>>>(bcount, bbase, bcur, row_ptr, nb, N, E);

    // 4) coarse partition of packed (hloc,t) by h>>BSHIFT into tmp
    {
        int blocks = (E + CHUNK - 1) / CHUNK;
        partition_edges<<<blocks, 256, 0, stream>>>(hl, tl, bcur, tmp, E, nb);
    }

    // 5) per-bucket CSR build + fused x0s convert
    build_csr_bucket<<<nb, 512, 0, stream>>>(tmp, bbase, row_ptr, rdeg, rsq, col,
                                             ue, ie, n_users, x0sh, N);

    // 6) layer 1: x1s = rdeg^2 * sum(x0s)  (8-lane group per node)
    {
        int nodes_per_block = 256 / 8;
        int blocks = (N + nodes_per_block - 1) / nodes_per_block;
        spmm_pull_l1<<<blocks, 256, 0, stream>>>(row_ptr, col, rdeg, x0s, x1s, N);
    }

    // 7) layer 2 + finalize fused (8-lane group per node)
    {
        int nodes_per_block = 256 / 8;
        int blocks = (N + nodes_per_block - 1) / nodes_per_block;
        spmm_l2_finalize<<<blocks, 256, 0, stream>>>(row_ptr, col, rdeg, rsq,
                                                     x0s, x1s, out, N);
    }
}

// Round 13
// 324.498 us; speedup vs baseline: 2.2126x; 1.0269x over previous
//
#include <hip/hip_runtime.h>

#define DIM 64
#define CHUNK 16384       // edges per partition block
#define BSHIFT 9          // 512 nodes per coarse bucket
#define BSIZE (1 << BSHIFT)
#define MAXB 512          // max coarse buckets (N<=262144)
#define TBITS 21          // bits for t in packed tmp (N < 2^21)
#define TMASK ((1u << TBITS) - 1u)

// ---- bf16 helpers (RNE) ----
__device__ __forceinline__ unsigned f2bf(float f) {
    unsigned u = __float_as_uint(f);
    return (u + 0x7FFFu + ((u >> 16) & 1u)) >> 16;
}
__device__ __forceinline__ float bflo(unsigned u) {   // low u16 -> f32
    return __uint_as_float(u << 16);
}
__device__ __forceinline__ float bfhi(unsigned u) {   // high u16 -> f32
    return __uint_as_float(u & 0xFFFF0000u);
}

// ---------------- zero u32 region ----------------
__global__ void zero_u32(unsigned* __restrict__ p, int n) {
    int i = blockIdx.x * blockDim.x + threadIdx.x;
    int stride = gridDim.x * blockDim.x;
    for (; i < n; i += stride) p[i] = 0u;
}

// ---------------- coarse bucket histogram (512 bins, LDS + global merge) ----------------
__global__ void bucket_hist(const int* __restrict__ h, unsigned* __restrict__ bcount,
                            int E, int nb) {
    __shared__ unsigned s[MAXB];
    for (int i = threadIdx.x; i < nb; i += blockDim.x) s[i] = 0u;
    __syncthreads();
    int i = blockIdx.x * blockDim.x + threadIdx.x;
    int stride = gridDim.x * blockDim.x;
    for (; i < E; i += stride) atomicAdd(&s[((unsigned)h[i]) >> BSHIFT], 1u);
    __syncthreads();
    for (int i = threadIdx.x; i < nb; i += blockDim.x)
        if (s[i]) atomicAdd(&bcount[i], s[i]);
}

// ---------------- scan bucket counts -> bbase/bcur (1 block of MAXB threads) ----------------
__global__ void bucket_scan(const unsigned* __restrict__ bcount,
                            unsigned* __restrict__ bbase, unsigned* __restrict__ bcur,
                            unsigned* __restrict__ row_ptr, int nb, int N, int E) {
    __shared__ unsigned s[MAXB];
    int tid = threadIdx.x;
    unsigned v = (tid < nb) ? bcount[tid] : 0u;
    s[tid] = v; __syncthreads();
    for (int off = 1; off < MAXB; off <<= 1) {
        unsigned t = (tid >= off) ? s[tid - off] : 0u;
        __syncthreads();
        s[tid] += t; __syncthreads();
    }
    if (tid < nb) {
        unsigned ex = s[tid] - v;   // exclusive
        bbase[tid] = ex;
        bcur[tid] = ex;
    }
    if (tid == 0) {
        bbase[nb] = (unsigned)E;
        row_ptr[N] = (unsigned)E;
    }
}

// ---------------- coarse partition: packed (hloc,t) -> bucket-contiguous tmp ----------------
__global__ void partition_edges(const int* __restrict__ h, const int* __restrict__ t,
                                unsigned* __restrict__ bcur, unsigned* __restrict__ tmp,
                                int E, int nb) {
    __shared__ unsigned cnt[MAXB];
    int tid = threadIdx.x;
    long start = (long)blockIdx.x * CHUNK;
    long end = start + CHUNK; if (end > E) end = E;
    for (int i = tid; i < nb; i += blockDim.x) cnt[i] = 0u;
    __syncthreads();
    for (long i = start + tid; i < end; i += blockDim.x)
        atomicAdd(&cnt[((unsigned)h[i]) >> BSHIFT], 1u);
    __syncthreads();
    for (int i = tid; i < nb; i += blockDim.x) {
        unsigned c = cnt[i];
        cnt[i] = c ? atomicAdd(&bcur[i], c) : 0u;   // reserve chunk; cnt becomes cursor
    }
    __syncthreads();
    for (long i = start + tid; i < end; i += blockDim.x) {
        unsigned hn = (unsigned)h[i], tn = (unsigned)t[i];
        unsigned pos = atomicAdd(&cnt[hn >> BSHIFT], 1u);
        tmp[pos] = ((hn & (BSIZE - 1)) << TBITS) | tn;   // 9-bit hloc | 21-bit t
    }
}

// ---------------- per-bucket CSR build + fused x0s convert ----------------
// One block (512 thr) per 512-node bucket: LDS histogram -> 1-elem/thread scan
// -> row_ptr/rdeg/rsq, LDS-atomic col placement, fused pre-scaled bf16 convert.
// 489 blocks ~= 2 per CU -> barrier/latency phases overlap across blocks.
__global__ void build_csr_bucket(const unsigned* __restrict__ tmp,
                                 const unsigned* __restrict__ bbase,
                                 unsigned* __restrict__ row_ptr,
                                 float* __restrict__ rdeg,
                                 float* __restrict__ rsq,
                                 int* __restrict__ col,
                                 const float* __restrict__ ue,
                                 const float* __restrict__ ie,
                                 int n_users,
                                 unsigned short* __restrict__ x0s, int N) {
    __shared__ unsigned cnt[BSIZE];
    __shared__ unsigned cur[BSIZE];
    __shared__ unsigned ts[BSIZE];
    int b = blockIdx.x;
    int tid = threadIdx.x;
    unsigned e0 = bbase[b], e1 = bbase[b + 1];
    int nlo = b << BSHIFT;
    int nloc = N - nlo; if (nloc > BSIZE) nloc = BSIZE;
    cnt[tid] = 0u;
    __syncthreads();
    for (unsigned i = e0 + tid; i < e1; i += BSIZE)
        atomicAdd(&cnt[tmp[i] >> TBITS], 1u);
    __syncthreads();
    // exclusive scan, one element per thread
    unsigned myc = cnt[tid];
    ts[tid] = myc; __syncthreads();
    for (int off = 1; off < BSIZE; off <<= 1) {
        unsigned t = (tid >= off) ? ts[tid - off] : 0u;
        __syncthreads();
        ts[tid] += t; __syncthreads();
    }
    unsigned off0 = ts[tid] - myc;
    if (tid < nloc) {
        float d = fmaxf((float)myc, 1.0f);
        cur[tid] = off0;
        row_ptr[nlo + tid] = e0 + off0;
        rdeg[nlo + tid] = rsqrtf(d);
        rsq[nlo + tid]  = sqrtf(d);
    }
    __syncthreads();
    // place edges (LDS atomics only; col window ~32KB, L2-local)
    for (unsigned i = e0 + tid; i < e1; i += BSIZE) {
        unsigned pk = tmp[i];
        unsigned pos = e0 + atomicAdd(&cur[pk >> TBITS], 1u);
        col[pos] = (int)(pk & TMASK);
    }
    // fused convert: this bucket's rows -> pre-scaled bf16 x0s (cnt intact)
    long nu_elems = (long)n_users * DIM;
    int total = nloc * 16;   // 16 float4-chunks per 64-dim row
    for (int idx = tid; idx < total; idx += BSIZE) {
        int i = idx >> 4, j = idx & 15;
        long n = (long)(nlo + i);
        long elem = n * DIM + j * 4;
        const float* src = (elem < nu_elems) ? ue + elem : ie + (elem - nu_elems);
        float rd = rsqrtf(fmaxf((float)cnt[i], 1.0f));
        float4 v = *(const float4*)src;
        ushort4 o;
        o.x = (unsigned short)f2bf(rd * v.x); o.y = (unsigned short)f2bf(rd * v.y);
        o.z = (unsigned short)f2bf(rd * v.z); o.w = (unsigned short)f2bf(rd * v.w);
        *(ushort4*)(x0s + elem) = o;
    }
}

// ---------------- pull SpMM layer 1: x1s = rdeg^2 * (sum of x0s rows) ----------------
// One 8-lane group per node (8 nodes/wave), lane owns 8 dims (uint4 = 16B),
// 4 edges unrolled -> up to 32 independent gathers in flight per wave.
__global__ void spmm_pull_l1(const unsigned* __restrict__ rp,
                             const int* __restrict__ col,
                             const float* __restrict__ rdeg,
                             const uint4* __restrict__ x0s,
                             uint4* __restrict__ x1s, int N) {
    int node = blockIdx.x * (blockDim.x >> 3) + (threadIdx.x >> 3);
    int l = threadIdx.x & 7;
    if (node >= N) return;
    int e0 = (int)rp[node], e1 = (int)rp[node + 1];
    float a0 = 0.f, a1 = 0.f, a2 = 0.f, a3 = 0.f;
    float a4 = 0.f, a5 = 0.f, a6 = 0.f, a7 = 0.f;
    int e = e0;
    for (; e + 4 <= e1; e += 4) {
        int c0 = col[e], c1 = col[e + 1], c2 = col[e + 2], c3 = col[e + 3];
        uint4 u0 = x0s[((size_t)c0 << 3) + l];
        uint4 u1 = x0s[((size_t)c1 << 3) + l];
        uint4 u2 = x0s[((size_t)c2 << 3) + l];
        uint4 u3 = x0s[((size_t)c3 << 3) + l];
        a0 += bflo(u0.x) + bflo(u1.x) + bflo(u2.x) + bflo(u3.x);
        a1 += bfhi(u0.x) + bfhi(u1.x) + bfhi(u2.x) + bfhi(u3.x);
        a2 += bflo(u0.y) + bflo(u1.y) + bflo(u2.y) + bflo(u3.y);
        a3 += bfhi(u0.y) + bfhi(u1.y) + bfhi(u2.y) + bfhi(u3.y);
        a4 += bflo(u0.z) + bflo(u1.z) + bflo(u2.z) + bflo(u3.z);
        a5 += bfhi(u0.z) + bfhi(u1.z) + bfhi(u2.z) + bfhi(u3.z);
        a6 += bflo(u0.w) + bflo(u1.w) + bflo(u2.w) + bflo(u3.w);
        a7 += bfhi(u0.w) + bfhi(u1.w) + bfhi(u2.w) + bfhi(u3.w);
    }
    for (; e < e1; ++e) {
        int c = col[e];
        uint4 u = x0s[((size_t)c << 3) + l];
        a0 += bflo(u.x); a1 += bfhi(u.x);
        a2 += bflo(u.y); a3 += bfhi(u.y);
        a4 += bflo(u.z); a5 += bfhi(u.z);
        a6 += bflo(u.w); a7 += bfhi(u.w);
    }
    float rd = rdeg[node];
    float rd2 = rd * rd;              // x1s = rdeg * x1 = rdeg^2 * sum
    uint4 o;
    o.x = (f2bf(rd2 * a1) << 16) | f2bf(rd2 * a0);
    o.y = (f2bf(rd2 * a3) << 16) | f2bf(rd2 * a2);
    o.z = (f2bf(rd2 * a5) << 16) | f2bf(rd2 * a4);
    o.w = (f2bf(rd2 * a7) << 16) | f2bf(rd2 * a6);
    x1s[((size_t)node << 3) + l] = o;
}

// ---------------- pull SpMM layer 2 fused with finalize ----------------
__global__ void spmm_l2_finalize(const unsigned* __restrict__ rp,
                                 const int* __restrict__ col,
                                 const float* __restrict__ rdeg,
                                 const float* __restrict__ rsq,
                                 const uint4* __restrict__ x0s,
                                 const uint4* __restrict__ x1s,
                                 float* __restrict__ out, int N) {
    int node = blockIdx.x * (blockDim.x >> 3) + (threadIdx.x >> 3);
    int l = threadIdx.x & 7;
    if (node >= N) return;
    int e0 = (int)rp[node], e1 = (int)rp[node + 1];
    float a0 = 0.f, a1 = 0.f, a2 = 0.f, a3 = 0.f;
    float a4 = 0.f, a5 = 0.f, a6 = 0.f, a7 = 0.f;
    int e = e0;
    for (; e + 4 <= e1; e += 4) {
        int c0 = col[e], c1 = col[e + 1], c2 = col[e + 2], c3 = col[e + 3];
        uint4 u0 = x1s[((size_t)c0 << 3) + l];
        uint4 u1 = x1s[((size_t)c1 << 3) + l];
        uint4 u2 = x1s[((size_t)c2 << 3) + l];
        uint4 u3 = x1s[((size_t)c3 << 3) + l];
        a0 += bflo(u0.x) + bflo(u1.x) + bflo(u2.x) + bflo(u3.x);
        a1 += bfhi(u0.x) + bfhi(u1.x) + bfhi(u2.x) + bfhi(u3.x);
        a2 += bflo(u0.y) + bflo(u1.y) + bflo(u2.y) + bflo(u3.y);
        a3 += bfhi(u0.y) + bfhi(u1.y) + bfhi(u2.y) + bfhi(u3.y);
        a4 += bflo(u0.z) + bflo(u1.z) + bflo(u2.z) + bflo(u3.z);
        a5 += bfhi(u0.z) + bfhi(u1.z) + bfhi(u2.z) + bfhi(u3.z);
        a6 += bflo(u0.w) + bflo(u1.w) + bflo(u2.w) + bflo(u3.w);
        a7 += bfhi(u0.w) + bfhi(u1.w) + bfhi(u2.w) + bfhi(u3.w);
    }
    for (; e < e1; ++e) {
        int c = col[e];
        uint4 u = x1s[((size_t)c << 3) + l];
        a0 += bflo(u.x); a1 += bfhi(u.x);
        a2 += bflo(u.y); a3 += bfhi(u.y);
        a4 += bflo(u.z); a5 += bfhi(u.z);
        a6 += bflo(u.w); a7 += bfhi(u.w);
    }
    float rd = rdeg[node];
    a0 *= rd; a1 *= rd; a2 *= rd; a3 *= rd;
    a4 *= rd; a5 *= rd; a6 *= rd; a7 *= rd;     // x2 = rdeg * sum(x1s)
    // self terms: x0 = x0s*rsq, x1 = x1s*rsq
    float rq = rsq[node];
    uint4 u0 = x0s[((size_t)node << 3) + l];
    uint4 u1 = x1s[((size_t)node << 3) + l];
    float v0 = (rq * (bflo(u0.x) + bflo(u1.x)) + a0) * (1.0f / 3.0f);
    float v1 = (rq * (bfhi(u0.x) + bfhi(u1.x)) + a1) * (1.0f / 3.0f);
    float v2 = (rq * (bflo(u0.y) + bflo(u1.y)) + a2) * (1.0f / 3.0f);
    float v3 = (rq * (bfhi(u0.y) + bfhi(u1.y)) + a3) * (1.0f / 3.0f);
    float v4 = (rq * (bflo(u0.z) + bflo(u1.z)) + a4) * (1.0f / 3.0f);
    float v5 = (rq * (bfhi(u0.z) + bfhi(u1.z)) + a5) * (1.0f / 3.0f);
    float v6 = (rq * (bflo(u0.w) + bflo(u1.w)) + a6) * (1.0f / 3.0f);
    float v7 = (rq * (bfhi(u0.w) + bfhi(u1.w)) + a7) * (1.0f / 3.0f);
    // sum of squares across the 8-lane group
    float ss = v0*v0 + v1*v1 + v2*v2 + v3*v3 + v4*v4 + v5*v5 + v6*v6 + v7*v7;
    ss += __shfl_xor(ss, 1);
    ss += __shfl_xor(ss, 2);
    ss += __shfl_xor(ss, 4);
    float theta = fmaxf(sqrtf(ss), 1e-7f);
    float ex  = __expf(theta);
    float exi = __builtin_amdgcn_rcpf(ex);
    float sh = 0.5f * (ex - exi);
    float ch = 0.5f * (ex + exi);
    float sc = sh * __builtin_amdgcn_rcpf(theta);
    float* o = out + (long)node * 129;
    *(float4*)(o + 8 * l)     = make_float4(v0, v1, v2, v3);   // dims 0..63
    *(float4*)(o + 8 * l + 4) = make_float4(v4, v5, v6, v7);
    if (l == 0) o[64] = ch;                                    // time coordinate
    *(float4*)(o + 65 + 8 * l)     = make_float4(sc*v0, sc*v1, sc*v2, sc*v3);
    *(float4*)(o + 65 + 8 * l + 4) = make_float4(sc*v4, sc*v5, sc*v6, sc*v7);
}

extern "C" void kernel_launch(void* const* d_in, const int* in_sizes, int n_in,
                              void* d_out, int out_size, void* d_ws, size_t ws_size,
                              hipStream_t stream) {
    const float* ue = (const float*)d_in[0];
    const float* ie = (const float*)d_in[1];
    const int*   hl = (const int*)d_in[2];
    const int*   tl = (const int*)d_in[3];
    float* out = (float*)d_out;

    const int n_users = in_sizes[0] / DIM;
    const int n_items = in_sizes[1] / DIM;
    const int N = n_users + n_items;
    const int E = in_sizes[2];
    const int nb = (N + BSIZE - 1) >> BSHIFT;   // coarse buckets (<=MAXB)
    const long M = (long)N * DIM;

    // workspace layout (256B-aligned):
    // row_ptr[N+1] | rdeg[N] | rsq[N] | bcount | bbase | bcur
    //   | col[E] | tmp[E u32] | x0s[M u16] | x1s[M u16]
    auto align = [](size_t x) { return (x + 255) & ~(size_t)255; };
    char* p = (char*)d_ws;
    unsigned* row_ptr = (unsigned*)p;            p += align((size_t)(N + 1) * 4);
    float*    rdeg    = (float*)p;               p += align((size_t)N * 4);
    float*    rsq     = (float*)p;               p += align((size_t)N * 4);
    unsigned* bcount  = (unsigned*)p;            p += align((size_t)MAXB * 4);
    unsigned* bbase   = (unsigned*)p;            p += align((size_t)(MAXB + 1) * 4);
    unsigned* bcur    = (unsigned*)p;            p += align((size_t)MAXB * 4);
    int*      col     = (int*)p;                 p += align((size_t)E * 4);
    unsigned* tmp     = (unsigned*)p;            p += align((size_t)E * 4);
    unsigned short* x0sh = (unsigned short*)p;   p += align((size_t)M * 2);
    unsigned short* x1sh = (unsigned short*)p;   // M u16
    const uint4* x0s = (const uint4*)x0sh;
    uint4* x1s = (uint4*)x1sh;

    // 1) zero bucket counts
    zero_u32<<<1, 256, 0, stream>>>(bcount, MAXB);

    // 2) coarse bucket histogram
    bucket_hist<<<512, 256, 0, stream>>>(hl, bcount, E, nb);

    // 3) scan bucket counts -> bbase/bcur; row_ptr[N]=E
    bucket_scan<<<1, MAXB, 0, stream>>>(bcount, bbase, bcur, row_ptr, nb, N, E);

    // 4) coarse partition of packed (hloc,t) by h>>BSHIFT into tmp
    {
        int blocks = (E + CHUNK - 1) / CHUNK;
        partition_edges<<<blocks, 256, 0, stream>>>(hl, tl, bcur, tmp, E, nb);
    }

    // 5) per-bucket CSR build + fused x0s convert (489 blocks ~= 2/CU)
    build_csr_bucket<<<nb, BSIZE, 0, stream>>>(tmp, bbase, row_ptr, rdeg, rsq, col,
                                               ue, ie, n_users, x0sh, N);

    // 6) layer 1: x1s = rdeg^2 * sum(x0s)  (8-lane group per node)
    {
        int nodes_per_block = 256 / 8;
        int blocks = (N + nodes_per_block - 1) / nodes_per_block;
        spmm_pull_l1<<<blocks, 256, 0, stream>>>(row_ptr, col, rdeg, x0s, x1s, N);
    }

    // 7) layer 2 + finalize fused (8-lane group per node)
    {
        int nodes_per_block = 256 / 8;
        int blocks = (N + nodes_per_block - 1) / nodes_per_block;
        spmm_l2_finalize<<<blocks, 256, 0, stream>>>(row_ptr, col, rdeg, rsq,
                                                     x0s, x1s, out, N);
    }
}